// Round 11
// baseline (419.943 us; speedup 1.0000x reference)
//
#include <hip/hip_runtime.h>

typedef __bf16 bf16x8 __attribute__((ext_vector_type(8)));
typedef __bf16 bf16x4 __attribute__((ext_vector_type(4)));
typedef float  f32x4  __attribute__((ext_vector_type(4)));
typedef int    i32x4  __attribute__((ext_vector_type(4)));

typedef __attribute__((address_space(1))) unsigned int as1_u32;
typedef __attribute__((address_space(3))) unsigned int as3_u32;

#define DEVI __device__ __forceinline__

DEVI unsigned short f2bf(float f) {
    union { float f; unsigned u; } v; v.f = f;
    unsigned r = (v.u + 0x7fffu + ((v.u >> 16) & 1u)) >> 16;
    return (unsigned short)r;
}

// direct global->LDS 16B: lane L's 16B lands at ldsbase + L*16
DEVI void gload16(const void* g, void* l) {
    __builtin_amdgcn_global_load_lds((const as1_u32*)g, (as3_u32*)l, 16, 0, 0);
}

// softmax(x/8) = exp2(x * 0.125 * log2(e)); scale folded into Q projection.
#define C_EXP 0.18033688011112042f
// -10000 * log2(e)
#define MASK_ADD (-14426.950408889634f)

// ---------------------------------------------------------------------------
// f32 -> bf16 bulk convert (n8 = elements/8)
// ---------------------------------------------------------------------------
__global__ __launch_bounds__(256) void cvt_kernel(const float* __restrict__ in,
                                                  unsigned short* __restrict__ out,
                                                  int n8) {
    const int stride = gridDim.x * 256;
    for (int idx = blockIdx.x * 256 + threadIdx.x; idx < n8; idx += stride) {
        const f32x4 a = *(const f32x4*)(in + (size_t)idx * 8);
        const f32x4 b = *(const f32x4*)(in + (size_t)idx * 8 + 4);
        union { bf16x4 v[2]; i32x4 q; } u;
        u.v[0] = __builtin_convertvector(a, bf16x4);
        u.v[1] = __builtin_convertvector(b, bf16x4);
        *(i32x4*)(out + (size_t)idx * 8) = u.q;
    }
}

// ---------------------------------------------------------------------------
// Transpose 4x (1024x1024) f32 -> bf16: WT[n][k] = W[k][n]*scale, z selects.
// ---------------------------------------------------------------------------
__global__ __launch_bounds__(256) void wtrans_kernel(const float* __restrict__ W0,
                                                     const float* __restrict__ W1,
                                                     const float* __restrict__ W2,
                                                     const float* __restrict__ W3,
                                                     unsigned short* __restrict__ T0,
                                                     unsigned short* __restrict__ T1,
                                                     unsigned short* __restrict__ T2,
                                                     unsigned short* __restrict__ T3) {
    __shared__ float tile[64][65];
    const float* W;
    unsigned short* WT;
    float scale = 1.0f;
    switch (blockIdx.z) {
        case 0:  W = W0; WT = T0; scale = C_EXP; break;
        case 1:  W = W1; WT = T1; break;
        case 2:  W = W2; WT = T2; break;
        default: W = W3; WT = T3; break;
    }
    const int k0 = blockIdx.x * 64, n0 = blockIdx.y * 64;
    const int i = threadIdx.x;
    const int c4 = (i & 15) * 4, rbase = i >> 4;
    for (int rr = 0; rr < 4; ++rr) {
        const int kl = rbase + rr * 16;
        const float4 v = *(const float4*)(W + (size_t)(k0 + kl) * 1024 + n0 + c4);
        tile[kl][c4 + 0] = v.x; tile[kl][c4 + 1] = v.y;
        tile[kl][c4 + 2] = v.z; tile[kl][c4 + 3] = v.w;
    }
    __syncthreads();
    for (int rr = 0; rr < 4; ++rr) {
        const int nl = rbase + rr * 16;
        ushort4 o;
        o.x = f2bf(tile[c4 + 0][nl] * scale); o.y = f2bf(tile[c4 + 1][nl] * scale);
        o.z = f2bf(tile[c4 + 2][nl] * scale); o.w = f2bf(tile[c4 + 3][nl] * scale);
        *(ushort4*)(WT + (size_t)(n0 + nl) * 1024 + k0 + c4) = o;
    }
}

// ---------------------------------------------------------------------------
// Mask not-all-true bits: word[(b*16+tb128)] bit si set if any zero in the
// (b, 128-row t-tile, 64-col s-tile). mask is int32. flagsW pre-zeroed.
// ---------------------------------------------------------------------------
__global__ __launch_bounds__(256) void maskflag_kernel(const int* __restrict__ mask,
                                                       unsigned* __restrict__ flagsW) {
    const int bid = blockIdx.x;
    const int b = bid >> 9, rem = bid & 511;
    const int tb = rem >> 5, si = rem & 31;
    const int i = threadIdx.x;
    const int t = tb * 128 + (i >> 1);
    const int s = si * 64 + (i & 1) * 32;
    const uint4* p = (const uint4*)(mask + ((size_t)(b * 2048 + t)) * 2048 + s);
    int ok = 1;
    #pragma unroll
    for (int u = 0; u < 8; ++u) {
        const uint4 a = p[u];
        ok &= (a.x != 0) & (a.y != 0) & (a.z != 0) & (a.w != 0);
    }
    int all = __syncthreads_and(ok);
    if (i == 0 && !all) atomicOr(&flagsW[b * 16 + tb], 1u << si);
}

// ---------------------------------------------------------------------------
// Unified bf16 GEMM: C[m,n] = A[m,:] . BT[n,:] + bias[n]*bscale
// 128x128 tile, BK=32, 2-buffer LDS (32KB -> 5 blocks/CU), COUNTED-vmcnt
// pipeline (T4): per iter {issue 4 gloads(it+1); s_waitcnt vmcnt(4);
// s_barrier; 8 ds_read + 16 MFMA; lgkmcnt(0); s_barrier} - prefetch loads
// stay in flight across the barrier, never drained to 0 in the main loop.
// XOR chunk-swizzle swz4(r) = (r^(r>>2))&3 on stage source and reads.
// XCD-swizzled 1D grid: NB n-blocks per m-panel land on one XCD.
// MODE 0: bf16 scatter [b][h][t][c]        (Q)
// MODE 2: f32 linear [m][n]                (output)
// MODE 3: merged K|V: n<1024 -> K scatter; n>=1024 -> V^T scatter.
// ---------------------------------------------------------------------------
template <int MODE, int NB>
__global__ __launch_bounds__(256, 5) void mm_kernel(const unsigned short* __restrict__ A,
                                                    const unsigned short* __restrict__ BT,
                                                    const float* __restrict__ biasK,
                                                    const float* __restrict__ biasV,
                                                    float bscale,
                                                    void* __restrict__ OvK,
                                                    void* __restrict__ OvV) {
    __shared__ __align__(16) unsigned short Ab[2][128 * 32];
    __shared__ __align__(16) unsigned short Bb[2][128 * 32];
    const int bid = blockIdx.x;
    const int xcd = bid & 7, jj = bid >> 3;
    const int n0 = (jj % NB) * 128;
    const int m0 = ((jj / NB) * 8 + xcd) * 128;
    const int i = threadIdx.x, w = i >> 6, l = i & 63;
    const int wm = w >> 1, wn = w & 1;
    const int c = l & 15, g = l >> 4;

    f32x4 acc[4][4] = {};

    // staging: one gload covers 16 rows (lane L -> row L>>2, slot L&3 of 4x8-elem
    // chunks); source chunk = slot ^ swz4(row) so LDS slot s of row r holds
    // global chunk s ^ swz4(r), swz4(r) = (r^(r>>2))&3. Wave w stages rows
    // [w*32, w*32+32) via u=0,1.
    const int srow4 = l >> 2, sslot4 = l & 3;
    const unsigned short* As[2];
    const unsigned short* Bs[2];
    unsigned lofs[2];
    #pragma unroll
    for (int u = 0; u < 2; ++u) {
        const int rl = w * 32 + u * 16 + srow4;
        const int ch = sslot4 ^ ((rl ^ (rl >> 2)) & 3);
        As[u] = A  + (size_t)(m0 + rl) * 1024 + ch * 8;
        Bs[u] = BT + (size_t)(n0 + rl) * 1024 + ch * 8;
        lofs[u] = (unsigned)((w * 32 + u * 16) * 32);
    }

    // read-side row swizzles
    int rsA[4], rsB[4];
    #pragma unroll
    for (int f = 0; f < 4; ++f) {
        const int ra = wm * 64 + f * 16 + c;
        const int rb = wn * 64 + f * 16 + c;
        rsA[f] = (ra ^ (ra >> 2)) & 3;
        rsB[f] = (rb ^ (rb >> 2)) & 3;
    }

    // prologue: stage k-tile 0 into buffer 0
    #pragma unroll
    for (int u = 0; u < 2; ++u) {
        gload16(As[u], &Ab[0][lofs[u]]);
        gload16(Bs[u], &Bb[0][lofs[u]]);
    }

    #pragma unroll 2
    for (int it = 0; it < 31; ++it) {
        const int bufc = it & 1, bufn = bufc ^ 1;
        // issue next k-tile stage; these 4 loads stay in flight across the
        // barrier (counted vmcnt) - buf[bufn] was last read at iter it-1,
        // protected by iter it-1's trailing barrier.
        #pragma unroll
        for (int u = 0; u < 2; ++u) {
            gload16(As[u] + (it + 1) * 32, &Ab[bufn][lofs[u]]);
            gload16(Bs[u] + (it + 1) * 32, &Bb[bufn][lofs[u]]);
        }
        asm volatile("s_waitcnt vmcnt(4)" ::: "memory");   // stage(it) done
        __builtin_amdgcn_s_barrier();                      // visible to all
        bf16x8 af[4], bfr[4];
        #pragma unroll
        for (int f = 0; f < 4; ++f) {
            af[f]  = *(const bf16x8*)&Ab[bufc][(wm * 64 + f * 16 + c) * 32 + ((g ^ rsA[f]) * 8)];
            bfr[f] = *(const bf16x8*)&Bb[bufc][(wn * 64 + f * 16 + c) * 32 + ((g ^ rsB[f]) * 8)];
        }
        __builtin_amdgcn_s_setprio(1);
        #pragma unroll
        for (int mf = 0; mf < 4; ++mf)
            #pragma unroll
            for (int nf = 0; nf < 4; ++nf)
                acc[mf][nf] = __builtin_amdgcn_mfma_f32_16x16x32_bf16(af[mf], bfr[nf], acc[mf][nf], 0, 0, 0);
        __builtin_amdgcn_s_setprio(0);
        asm volatile("s_waitcnt lgkmcnt(0)" ::: "memory"); // ds_reads retired
        __builtin_amdgcn_s_barrier();                      // safe to overwrite
    }
    // final iteration (it = 31, buf 1): nothing left to stage
    {
        asm volatile("s_waitcnt vmcnt(0)" ::: "memory");
        __builtin_amdgcn_s_barrier();
        bf16x8 af[4], bfr[4];
        #pragma unroll
        for (int f = 0; f < 4; ++f) {
            af[f]  = *(const bf16x8*)&Ab[1][(wm * 64 + f * 16 + c) * 32 + ((g ^ rsA[f]) * 8)];
            bfr[f] = *(const bf16x8*)&Bb[1][(wn * 64 + f * 16 + c) * 32 + ((g ^ rsB[f]) * 8)];
        }
        #pragma unroll
        for (int mf = 0; mf < 4; ++mf)
            #pragma unroll
            for (int nf = 0; nf < 4; ++nf)
                acc[mf][nf] = __builtin_amdgcn_mfma_f32_16x16x32_bf16(af[mf], bfr[nf], acc[mf][nf], 0, 0, 0);
    }

    #pragma unroll
    for (int nf = 0; nf < 4; ++nf) {
        const int n = n0 + wn * 64 + nf * 16 + c;
        if (MODE == 0 || (MODE == 3 && n0 < 1024)) {
            const float bv = biasK[n] * bscale;
            const int h = n >> 6, cc = n & 63;
            unsigned short* O = (unsigned short*)OvK;
            #pragma unroll
            for (int mf = 0; mf < 4; ++mf) {
                const int mbase = m0 + wm * 64 + mf * 16 + g * 4;
                const int b = mbase >> 11, t = mbase & 2047;
                #pragma unroll
                for (int r = 0; r < 4; ++r)
                    O[(((size_t)(b * 16 + h)) * 2048 + t + r) * 64 + cc] = f2bf(acc[mf][nf][r] + bv);
            }
        } else if (MODE == 3) {
            const int nn = n - 1024;
            const float bv = biasV[nn];
            const int h = nn >> 6, cc = nn & 63;
            unsigned short* O = (unsigned short*)OvV;
            #pragma unroll
            for (int mf = 0; mf < 4; ++mf) {
                const int mbase = m0 + wm * 64 + mf * 16 + g * 4;
                const int b = mbase >> 11, t = mbase & 2047;
                f32x4 v;
                #pragma unroll
                for (int r = 0; r < 4; ++r) v[r] = acc[mf][nf][r] + bv;
                bf16x4 pv = __builtin_convertvector(v, bf16x4);
                *(bf16x4*)(O + (((size_t)(b * 16 + h)) * 64 + cc) * 2048 + t) = pv;
            }
        } else {
            const float bv = biasK[n] * bscale;
            float* O = (float*)OvK;
            #pragma unroll
            for (int mf = 0; mf < 4; ++mf) {
                const int mbase = m0 + wm * 64 + mf * 16 + g * 4;
                #pragma unroll
                for (int r = 0; r < 4; ++r)
                    O[(size_t)(mbase + r) * 1024 + n] = acc[mf][nf][r] + bv;
            }
        }
    }
}

// ---------------------------------------------------------------------------
// Flash attention, swapped QK^T with PERMUTED K rows (P in registers, K32 PV).
// Each wave handles TWO 16-row t-groups (block = 128 Q rows, grid = 1024 =
// 4 blocks/CU; LDS 4x32KB = 128KB). Shared kf/vf LDS reads feed both groups.
// Flags bitword granularity = one block. setprio around MFMA clusters.
// XCD swizzle: each XCD owns 8 bh x 16 tb (K/V 4MB = L2-resident).
// ---------------------------------------------------------------------------
__global__ __launch_bounds__(256, 4) void attn_kernel(const unsigned short* __restrict__ Qp,
                                                      const unsigned short* __restrict__ Kp,
                                                      const unsigned short* __restrict__ VTp,
                                                      const int* __restrict__ mask,
                                                      const unsigned* __restrict__ flagsW,
                                                      unsigned short* __restrict__ attnb) {
    __shared__ __align__(16) unsigned short Kt[2][64 * 64];  // [s][dk], swizzled chunks
    __shared__ __align__(16) unsigned short Vt[2][64 * 64];  // [v][s],  swizzled chunks

    const int bid = blockIdx.x;
    const int xcd = bid & 7, jj = bid >> 3;       // jj in 0..127
    const int bh = xcd * 8 + (jj >> 4);           // 8 bh per XCD
    const int tb = jj & 15;                       // 16 x 128-row t-tiles
    const int b = bh >> 4, h = bh & 15;
    const int i = threadIdx.x, w = i >> 6, l = i & 63;
    const int c = l & 15, g = l >> 4;

    const unsigned short* Qb  = Qp  + (size_t)bh * 2048 * 64;
    const unsigned short* Kb  = Kp  + (size_t)bh * 2048 * 64;
    const unsigned short* VTb = VTp + (size_t)bh * 64 * 2048;

    const int twave = tb * 128 + w * 32;
    const int tA = twave + c, tB = twave + 16 + c;

    // not-all-true bits for this 128-row region (wave-uniform, to SGPR)
    const unsigned notall = __builtin_amdgcn_readfirstlane(flagsW[b * 16 + tb]);

    // Q as B-operand (K32): lane holds Q[t][dk = kq*32+g*8+j]
    bf16x8 qfA[2], qfB[2];
    #pragma unroll
    for (int kq = 0; kq < 2; ++kq) {
        qfA[kq] = *(const bf16x8*)(Qb + (size_t)tA * 64 + kq * 32 + g * 8);
        qfB[kq] = *(const bf16x8*)(Qb + (size_t)tB * 64 + kq * 32 + g * 8);
    }

    f32x4 oA[4] = {}, oB[4] = {};   // O^T accum: v = vm*16+g*4+r
    f32x4 daccA = {}, daccB = {};   // denominators via ones-MFMA
    const f32x4 zf = {};            // persistent zero C-operand

    bf16x8 ones8;
    #pragma unroll
    for (int j = 0; j < 8; ++j) ones8[j] = (__bf16)1.0f;

    // kf read rows (permuted) + chunk swizzles, per sm
    int rrow[4], rswz[4];
    #pragma unroll
    for (int sm = 0; sm < 4; ++sm) {
        rrow[sm] = (sm >> 1) * 32 + (c >> 2) * 8 + (sm & 1) * 4 + (c & 3);
        rswz[sm] = (rrow[sm] ^ (rrow[sm] >> 2)) & 7;
    }
    int vswz[4];
    #pragma unroll
    for (int vm = 0; vm < 4; ++vm) {
        const int rv = vm * 16 + c;
        vswz[vm] = (rv ^ (rv >> 2)) & 7;
    }

    // staging: lane L -> LDS (row = base + L>>3, slot L&7); source chunk
    // = (L&7) ^ swz(row) so LDS slot s of row r holds global chunk s ^ swz(r).
    const int srow = l >> 3, sslot = l & 7;

    // prologue: stage tile 0 into buffer 0; running stage pointers (tile 1)
    const unsigned short* kstage[2];
    const unsigned short* vstage[2];
    #pragma unroll
    for (int u = 0; u < 2; ++u) {
        const int row = w * 16 + u * 8 + srow;
        const int ch = sslot ^ ((row ^ (row >> 2)) & 7);
        gload16(Kb + (size_t)row * 64 + ch * 8, &Kt[0][(w * 16 + u * 8) * 64]);
        gload16(VTb + (size_t)row * 2048 + ch * 8, &Vt[0][(w * 16 + u * 8) * 64]);
        kstage[u] = Kb + (size_t)(64 + row) * 64 + ch * 8;
        vstage[u] = VTb + (size_t)row * 2048 + 64 + ch * 8;
    }
    __syncthreads();

    #pragma unroll 2
    for (int it = 0; it < 32; ++it) {
        const int buf = it & 1;
        const int s0 = it * 64;

        // issue next-tile stage (lands in buf^1; drained by end-of-iter barrier)
        if (it < 31) {
            #pragma unroll
            for (int u = 0; u < 2; ++u) {
                gload16(kstage[u], &Kt[buf ^ 1][(w * 16 + u * 8) * 64]);
                gload16(vstage[u], &Vt[buf ^ 1][(w * 16 + u * 8) * 64]);
                kstage[u] += 64 * 64;
                vstage[u] += 64;
            }
        }

        // QK^T swapped, permuted rows, both groups sharing kf:
        // scX[sm][r] = S^T at s = s0 + (sm>>1)*32 + g*8 + (sm&1)*4 + r
        f32x4 scA[4], scB[4];
        __builtin_amdgcn_s_setprio(1);
        #pragma unroll
        for (int sm = 0; sm < 4; ++sm) {
            #pragma unroll
            for (int kq = 0; kq < 2; ++kq) {
                const bf16x8 kf = *(const bf16x8*)&Kt[buf][rrow[sm] * 64 + (((kq * 4 + g) ^ rswz[sm]) * 8)];
                if (kq == 0) {
                    scA[sm] = __builtin_amdgcn_mfma_f32_16x16x32_bf16(kf, qfA[0], zf, 0, 0, 0);
                    scB[sm] = __builtin_amdgcn_mfma_f32_16x16x32_bf16(kf, qfB[0], zf, 0, 0, 0);
                } else {
                    scA[sm] = __builtin_amdgcn_mfma_f32_16x16x32_bf16(kf, qfA[1], scA[sm], 0, 0, 0);
                    scB[sm] = __builtin_amdgcn_mfma_f32_16x16x32_bf16(kf, qfB[1], scB[sm], 0, 0, 0);
                }
            }
        }
        __builtin_amdgcn_s_setprio(0);

        // mask fallback (exp2 domain), permuted s indexing (scalar-skipped)
        if (notall & (1u << it)) {
            #pragma unroll
            for (int sm = 0; sm < 4; ++sm)
                #pragma unroll
                for (int r = 0; r < 4; ++r) {
                    const int s = s0 + (sm >> 1) * 32 + g * 8 + (sm & 1) * 4 + r;
                    if (mask[(size_t)(b * 2048 + tA) * 2048 + s] == 0) scA[sm][r] += MASK_ADD;
                    if (mask[(size_t)(b * 2048 + tB) * 2048 + s] == 0) scB[sm][r] += MASK_ADD;
                }
        }

        // p = exp2(sc); pack directly into K32 PV B-fragments
        bf16x8 paA[2], paB[2];
        #pragma unroll
        for (int kv = 0; kv < 2; ++kv) {
            f32x4 a0, a1, b0, b1;
            #pragma unroll
            for (int r = 0; r < 4; ++r) {
                a0[r] = __builtin_amdgcn_exp2f(scA[kv * 2][r]);
                a1[r] = __builtin_amdgcn_exp2f(scA[kv * 2 + 1][r]);
                b0[r] = __builtin_amdgcn_exp2f(scB[kv * 2][r]);
                b1[r] = __builtin_amdgcn_exp2f(scB[kv * 2 + 1][r]);
            }
            union { struct { bf16x4 lo, hi; } hh; bf16x8 v; } ua, ub;
            ua.hh.lo = __builtin_convertvector(a0, bf16x4);
            ua.hh.hi = __builtin_convertvector(a1, bf16x4);
            ub.hh.lo = __builtin_convertvector(b0, bf16x4);
            ub.hh.hi = __builtin_convertvector(b1, bf16x4);
            paA[kv] = ua.v;
            paB[kv] = ub.v;
        }

        // PV (K32) + denominators, shared vf
        __builtin_amdgcn_s_setprio(1);
        #pragma unroll
        for (int kv = 0; kv < 2; ++kv) {
            daccA = __builtin_amdgcn_mfma_f32_16x16x32_bf16(ones8, paA[kv], daccA, 0, 0, 0);
            daccB = __builtin_amdgcn_mfma_f32_16x16x32_bf16(ones8, paB[kv], daccB, 0, 0, 0);
            #pragma unroll
            for (int vm = 0; vm < 4; ++vm) {
                const bf16x8 vf = *(const bf16x8*)&Vt[buf][(vm * 16 + c) * 64 + (((kv * 4 + g) ^ vswz[vm]) * 8)];
                oA[vm] = __builtin_amdgcn_mfma_f32_16x16x32_bf16(vf, paA[kv], oA[vm], 0, 0, 0);
                oB[vm] = __builtin_amdgcn_mfma_f32_16x16x32_bf16(vf, paB[kv], oB[vm], 0, 0, 0);
            }
        }
        __builtin_amdgcn_s_setprio(0);

        __syncthreads();  // drains vmcnt (stage) + lgkm, then barrier
    }

    const float invA = 1.0f / daccA[0];
    const float invB = 1.0f / daccB[0];

    // epilogue: attnb[(b*2048+t)*1024 + h*64 + v] = O^T[v][t] * inv
    #pragma unroll
    for (int vm = 0; vm < 4; ++vm) {
        f32x4 vA, vB;
        #pragma unroll
        for (int r = 0; r < 4; ++r) { vA[r] = oA[vm][r] * invA; vB[r] = oB[vm][r] * invB; }
        bf16x4 pA = __builtin_convertvector(vA, bf16x4);
        bf16x4 pB = __builtin_convertvector(vB, bf16x4);
        *(bf16x4*)(attnb + (size_t)(b * 2048 + tA) * 1024 + h * 64 + vm * 16 + g * 4) = pA;
        *(bf16x4*)(attnb + (size_t)(b * 2048 + tB) * 1024 + h * 64 + vm * 16 + g * 4) = pB;
    }
}

// ---------------------------------------------------------------------------
extern "C" void kernel_launch(void* const* d_in, const int* in_sizes, int n_in,
                              void* d_out, int out_size, void* d_ws, size_t ws_size,
                              hipStream_t stream) {
    const float* query = (const float*)d_in[0];
    const float* value = (const float*)d_in[1];
    const int*   mask  = (const int*)d_in[2];
    const float* Wq = (const float*)d_in[3];
    const float* bq = (const float*)d_in[4];
    const float* Wk = (const float*)d_in[5];
    const float* bk = (const float*)d_in[6];
    const float* Wv = (const float*)d_in[7];
    const float* bv = (const float*)d_in[8];
    const float* Wo = (const float*)d_in[9];
    const float* bo = (const float*)d_in[10];

    char* ws = (char*)d_ws;
    unsigned short* WqT   = (unsigned short*)(ws + ((size_t)0  << 20));  // 2 MB (x C_EXP)
    unsigned short* WkT   = (unsigned short*)(ws + ((size_t)2  << 20));  // 2 MB  } contiguous ->
    unsigned short* WvT   = (unsigned short*)(ws + ((size_t)4  << 20));  // 2 MB  } stacked KV BT
    unsigned short* WoT   = (unsigned short*)(ws + ((size_t)6  << 20));  // 2 MB
    unsigned*       flagsW= (unsigned*)      (ws + ((size_t)8  << 20));  // 256 B (bitwords)
    unsigned short* CONV  = (unsigned short*)(ws + ((size_t)9  << 20));  // 16 MB (Vbf16 -> Qbf16 -> attnb)
    unsigned short* Qp    = (unsigned short*)(ws + ((size_t)25 << 20));  // 16 MB (pre-scaled Q)
    unsigned short* Kp    = (unsigned short*)(ws + ((size_t)41 << 20));  // 16 MB
    unsigned short* VTp   = (unsigned short*)(ws + ((size_t)57 << 20));  // 16 MB ([bh][v][s])

    const int n8 = 8192 * 1024 / 8;

    hipMemsetAsync(flagsW, 0, 64 * sizeof(unsigned), stream);

    // value -> bf16; merged K|V projection consumes it (BT = WkT||WvT stacked)
    cvt_kernel<<<2048, 256, 0, stream>>>(value, CONV, n8);
    wtrans_kernel<<<dim3(16, 16, 4), 256, 0, stream>>>(Wq, Wk, Wv, Wo, WqT, WkT, WvT, WoT);
    maskflag_kernel<<<2048, 256, 0, stream>>>(mask, flagsW);
    mm_kernel<3, 16><<<1024, 256, 0, stream>>>(CONV, WkT, bk, bv, 1.0f, Kp, VTp);

    // query -> bf16 (reuses CONV; value-bf16 dead now)
    cvt_kernel<<<2048, 256, 0, stream>>>(query, CONV, n8);
    mm_kernel<0, 8><<<512, 256, 0, stream>>>(CONV, WqT, bq, bq, C_EXP, Qp, nullptr);

    // attention writes attnb into CONV (query-bf16 dead now)
    attn_kernel<<<1024, 256, 0, stream>>>(Qp, Kp, VTp, mask, flagsW, CONV);

    mm_kernel<2, 8><<<512, 256, 0, stream>>>(CONV, WoT, bo, bo, 1.0f, d_out, nullptr);
}

// Round 12
// 212.549 us; speedup vs baseline: 1.9757x; 1.9757x over previous
//
#include <hip/hip_runtime.h>

typedef __bf16 bf16x8 __attribute__((ext_vector_type(8)));
typedef __bf16 bf16x4 __attribute__((ext_vector_type(4)));
typedef float  f32x4  __attribute__((ext_vector_type(4)));
typedef int    i32x4  __attribute__((ext_vector_type(4)));

typedef __attribute__((address_space(1))) unsigned int as1_u32;
typedef __attribute__((address_space(3))) unsigned int as3_u32;

#define DEVI __device__ __forceinline__

DEVI unsigned short f2bf(float f) {
    union { float f; unsigned u; } v; v.f = f;
    unsigned r = (v.u + 0x7fffu + ((v.u >> 16) & 1u)) >> 16;
    return (unsigned short)r;
}

// direct global->LDS 16B: lane L's 16B lands at ldsbase + L*16
DEVI void gload16(const void* g, void* l) {
    __builtin_amdgcn_global_load_lds((const as1_u32*)g, (as3_u32*)l, 16, 0, 0);
}

// softmax(x/8) = exp2(x * 0.125 * log2(e)); scale folded into Q projection.
#define C_EXP 0.18033688011112042f
// -10000 * log2(e)
#define MASK_ADD (-14426.950408889634f)

// ---------------------------------------------------------------------------
// f32 -> bf16 bulk convert (n8 = elements/8)
// ---------------------------------------------------------------------------
__global__ __launch_bounds__(256) void cvt_kernel(const float* __restrict__ in,
                                                  unsigned short* __restrict__ out,
                                                  int n8) {
    const int stride = gridDim.x * 256;
    for (int idx = blockIdx.x * 256 + threadIdx.x; idx < n8; idx += stride) {
        const f32x4 a = *(const f32x4*)(in + (size_t)idx * 8);
        const f32x4 b = *(const f32x4*)(in + (size_t)idx * 8 + 4);
        union { bf16x4 v[2]; i32x4 q; } u;
        u.v[0] = __builtin_convertvector(a, bf16x4);
        u.v[1] = __builtin_convertvector(b, bf16x4);
        *(i32x4*)(out + (size_t)idx * 8) = u.q;
    }
}

// ---------------------------------------------------------------------------
// Transpose 4x (1024x1024) f32 -> bf16: WT[n][k] = W[k][n]*scale, z selects.
// ---------------------------------------------------------------------------
__global__ __launch_bounds__(256) void wtrans_kernel(const float* __restrict__ W0,
                                                     const float* __restrict__ W1,
                                                     const float* __restrict__ W2,
                                                     const float* __restrict__ W3,
                                                     unsigned short* __restrict__ T0,
                                                     unsigned short* __restrict__ T1,
                                                     unsigned short* __restrict__ T2,
                                                     unsigned short* __restrict__ T3) {
    __shared__ float tile[64][65];
    const float* W;
    unsigned short* WT;
    float scale = 1.0f;
    switch (blockIdx.z) {
        case 0:  W = W0; WT = T0; scale = C_EXP; break;
        case 1:  W = W1; WT = T1; break;
        case 2:  W = W2; WT = T2; break;
        default: W = W3; WT = T3; break;
    }
    const int k0 = blockIdx.x * 64, n0 = blockIdx.y * 64;
    const int i = threadIdx.x;
    const int c4 = (i & 15) * 4, rbase = i >> 4;
    for (int rr = 0; rr < 4; ++rr) {
        const int kl = rbase + rr * 16;
        const float4 v = *(const float4*)(W + (size_t)(k0 + kl) * 1024 + n0 + c4);
        tile[kl][c4 + 0] = v.x; tile[kl][c4 + 1] = v.y;
        tile[kl][c4 + 2] = v.z; tile[kl][c4 + 3] = v.w;
    }
    __syncthreads();
    for (int rr = 0; rr < 4; ++rr) {
        const int nl = rbase + rr * 16;
        ushort4 o;
        o.x = f2bf(tile[c4 + 0][nl] * scale); o.y = f2bf(tile[c4 + 1][nl] * scale);
        o.z = f2bf(tile[c4 + 2][nl] * scale); o.w = f2bf(tile[c4 + 3][nl] * scale);
        *(ushort4*)(WT + (size_t)(n0 + nl) * 1024 + k0 + c4) = o;
    }
}

// ---------------------------------------------------------------------------
// Mask not-all-true bits: word[(b*16+tb128)] bit si set if any zero in the
// (b, 128-row t-tile, 64-col s-tile). mask is int32. flagsW pre-zeroed.
// ---------------------------------------------------------------------------
__global__ __launch_bounds__(256) void maskflag_kernel(const int* __restrict__ mask,
                                                       unsigned* __restrict__ flagsW) {
    const int bid = blockIdx.x;
    const int b = bid >> 9, rem = bid & 511;
    const int tb = rem >> 5, si = rem & 31;
    const int i = threadIdx.x;
    const int t = tb * 128 + (i >> 1);
    const int s = si * 64 + (i & 1) * 32;
    const uint4* p = (const uint4*)(mask + ((size_t)(b * 2048 + t)) * 2048 + s);
    int ok = 1;
    #pragma unroll
    for (int u = 0; u < 8; ++u) {
        const uint4 a = p[u];
        ok &= (a.x != 0) & (a.y != 0) & (a.z != 0) & (a.w != 0);
    }
    int all = __syncthreads_and(ok);
    if (i == 0 && !all) atomicOr(&flagsW[b * 16 + tb], 1u << si);
}

// ---------------------------------------------------------------------------
// Unified bf16 GEMM: C[m,n] = A[m,:] . BT[n,:] + bias[n]*bscale
// 128x128 tile, BK=32, 2-buffer LDS (32KB), COUNTED-vmcnt pipeline (T4):
// per iter {issue 4 gloads(it+1); s_waitcnt vmcnt(4); s_barrier; 8 ds_read
// + 16 MFMA; lgkmcnt(0); s_barrier} - prefetch loads stay in flight across
// the barrier, never drained to 0 in the main loop.
// __launch_bounds__(256,4): 128-VGPR budget, NO spill (R11's (256,5) spilled
// acc to scratch: VGPR=48, WRITE_SIZE=448MB, 2x slower - fixed here).
// XOR chunk-swizzle swz4(r) = (r^(r>>2))&3 on stage source and reads.
// XCD-swizzled 1D grid: NB n-blocks per m-panel land on one XCD.
// MODE 0: bf16 scatter [b][h][t][c]        (Q)
// MODE 2: f32 linear [m][n]                (output)
// MODE 3: merged K|V: n<1024 -> K scatter; n>=1024 -> V^T scatter.
// ---------------------------------------------------------------------------
template <int MODE, int NB>
__global__ __launch_bounds__(256, 4) void mm_kernel(const unsigned short* __restrict__ A,
                                                    const unsigned short* __restrict__ BT,
                                                    const float* __restrict__ biasK,
                                                    const float* __restrict__ biasV,
                                                    float bscale,
                                                    void* __restrict__ OvK,
                                                    void* __restrict__ OvV) {
    __shared__ __align__(16) unsigned short Ab[2][128 * 32];
    __shared__ __align__(16) unsigned short Bb[2][128 * 32];
    const int bid = blockIdx.x;
    const int xcd = bid & 7, jj = bid >> 3;
    const int n0 = (jj % NB) * 128;
    const int m0 = ((jj / NB) * 8 + xcd) * 128;
    const int i = threadIdx.x, w = i >> 6, l = i & 63;
    const int wm = w >> 1, wn = w & 1;
    const int c = l & 15, g = l >> 4;

    f32x4 acc[4][4] = {};

    // staging: one gload covers 16 rows (lane L -> row L>>2, slot L&3 of 4x8-elem
    // chunks); source chunk = slot ^ swz4(row) so LDS slot s of row r holds
    // global chunk s ^ swz4(r), swz4(r) = (r^(r>>2))&3. Wave w stages rows
    // [w*32, w*32+32) via u=0,1.
    const int srow4 = l >> 2, sslot4 = l & 3;
    const unsigned short* As[2];
    const unsigned short* Bs[2];
    unsigned lofs[2];
    #pragma unroll
    for (int u = 0; u < 2; ++u) {
        const int rl = w * 32 + u * 16 + srow4;
        const int ch = sslot4 ^ ((rl ^ (rl >> 2)) & 3);
        As[u] = A  + (size_t)(m0 + rl) * 1024 + ch * 8;
        Bs[u] = BT + (size_t)(n0 + rl) * 1024 + ch * 8;
        lofs[u] = (unsigned)((w * 32 + u * 16) * 32);
    }

    // read-side row swizzles
    int rsA[4], rsB[4];
    #pragma unroll
    for (int f = 0; f < 4; ++f) {
        const int ra = wm * 64 + f * 16 + c;
        const int rb = wn * 64 + f * 16 + c;
        rsA[f] = (ra ^ (ra >> 2)) & 3;
        rsB[f] = (rb ^ (rb >> 2)) & 3;
    }

    // prologue: stage k-tile 0 into buffer 0
    #pragma unroll
    for (int u = 0; u < 2; ++u) {
        gload16(As[u], &Ab[0][lofs[u]]);
        gload16(Bs[u], &Bb[0][lofs[u]]);
    }

    #pragma unroll 2
    for (int it = 0; it < 31; ++it) {
        const int bufc = it & 1, bufn = bufc ^ 1;
        // issue next k-tile stage; these 4 loads stay in flight across the
        // barrier (counted vmcnt) - buf[bufn] was last read at iter it-1,
        // protected by iter it-1's trailing barrier.
        #pragma unroll
        for (int u = 0; u < 2; ++u) {
            gload16(As[u] + (it + 1) * 32, &Ab[bufn][lofs[u]]);
            gload16(Bs[u] + (it + 1) * 32, &Bb[bufn][lofs[u]]);
        }
        asm volatile("s_waitcnt vmcnt(4)" ::: "memory");   // stage(it) done
        __builtin_amdgcn_s_barrier();                      // visible to all
        bf16x8 af[4], bfr[4];
        #pragma unroll
        for (int f = 0; f < 4; ++f) {
            af[f]  = *(const bf16x8*)&Ab[bufc][(wm * 64 + f * 16 + c) * 32 + ((g ^ rsA[f]) * 8)];
            bfr[f] = *(const bf16x8*)&Bb[bufc][(wn * 64 + f * 16 + c) * 32 + ((g ^ rsB[f]) * 8)];
        }
        __builtin_amdgcn_s_setprio(1);
        #pragma unroll
        for (int mf = 0; mf < 4; ++mf)
            #pragma unroll
            for (int nf = 0; nf < 4; ++nf)
                acc[mf][nf] = __builtin_amdgcn_mfma_f32_16x16x32_bf16(af[mf], bfr[nf], acc[mf][nf], 0, 0, 0);
        __builtin_amdgcn_s_setprio(0);
        asm volatile("s_waitcnt lgkmcnt(0)" ::: "memory"); // ds_reads retired
        __builtin_amdgcn_s_barrier();                      // safe to overwrite
    }
    // final iteration (it = 31, buf 1): nothing left to stage
    {
        asm volatile("s_waitcnt vmcnt(0)" ::: "memory");
        __builtin_amdgcn_s_barrier();
        bf16x8 af[4], bfr[4];
        #pragma unroll
        for (int f = 0; f < 4; ++f) {
            af[f]  = *(const bf16x8*)&Ab[1][(wm * 64 + f * 16 + c) * 32 + ((g ^ rsA[f]) * 8)];
            bfr[f] = *(const bf16x8*)&Bb[1][(wn * 64 + f * 16 + c) * 32 + ((g ^ rsB[f]) * 8)];
        }
        #pragma unroll
        for (int mf = 0; mf < 4; ++mf)
            #pragma unroll
            for (int nf = 0; nf < 4; ++nf)
                acc[mf][nf] = __builtin_amdgcn_mfma_f32_16x16x32_bf16(af[mf], bfr[nf], acc[mf][nf], 0, 0, 0);
    }

    #pragma unroll
    for (int nf = 0; nf < 4; ++nf) {
        const int n = n0 + wn * 64 + nf * 16 + c;
        if (MODE == 0 || (MODE == 3 && n0 < 1024)) {
            const float bv = biasK[n] * bscale;
            const int h = n >> 6, cc = n & 63;
            unsigned short* O = (unsigned short*)OvK;
            #pragma unroll
            for (int mf = 0; mf < 4; ++mf) {
                const int mbase = m0 + wm * 64 + mf * 16 + g * 4;
                const int b = mbase >> 11, t = mbase & 2047;
                #pragma unroll
                for (int r = 0; r < 4; ++r)
                    O[(((size_t)(b * 16 + h)) * 2048 + t + r) * 64 + cc] = f2bf(acc[mf][nf][r] + bv);
            }
        } else if (MODE == 3) {
            const int nn = n - 1024;
            const float bv = biasV[nn];
            const int h = nn >> 6, cc = nn & 63;
            unsigned short* O = (unsigned short*)OvV;
            #pragma unroll
            for (int mf = 0; mf < 4; ++mf) {
                const int mbase = m0 + wm * 64 + mf * 16 + g * 4;
                const int b = mbase >> 11, t = mbase & 2047;
                f32x4 v;
                #pragma unroll
                for (int r = 0; r < 4; ++r) v[r] = acc[mf][nf][r] + bv;
                bf16x4 pv = __builtin_convertvector(v, bf16x4);
                *(bf16x4*)(O + (((size_t)(b * 16 + h)) * 64 + cc) * 2048 + t) = pv;
            }
        } else {
            const float bv = biasK[n] * bscale;
            float* O = (float*)OvK;
            #pragma unroll
            for (int mf = 0; mf < 4; ++mf) {
                const int mbase = m0 + wm * 64 + mf * 16 + g * 4;
                #pragma unroll
                for (int r = 0; r < 4; ++r)
                    O[(size_t)(mbase + r) * 1024 + n] = acc[mf][nf][r] + bv;
            }
        }
    }
}

// ---------------------------------------------------------------------------
// Flash attention, swapped QK^T with PERMUTED K rows (P in registers, K32 PV).
// Each wave handles TWO 16-row t-groups (block = 128 Q rows, grid = 1024 =
// 4 blocks/CU; LDS 4x32KB = 128KB). Shared kf/vf LDS reads feed both groups.
// Flags bitword granularity = one block. setprio around MFMA clusters.
// XCD swizzle: each XCD owns 8 bh x 16 tb (K/V 4MB = L2-resident).
// ---------------------------------------------------------------------------
__global__ __launch_bounds__(256, 4) void attn_kernel(const unsigned short* __restrict__ Qp,
                                                      const unsigned short* __restrict__ Kp,
                                                      const unsigned short* __restrict__ VTp,
                                                      const int* __restrict__ mask,
                                                      const unsigned* __restrict__ flagsW,
                                                      unsigned short* __restrict__ attnb) {
    __shared__ __align__(16) unsigned short Kt[2][64 * 64];  // [s][dk], swizzled chunks
    __shared__ __align__(16) unsigned short Vt[2][64 * 64];  // [v][s],  swizzled chunks

    const int bid = blockIdx.x;
    const int xcd = bid & 7, jj = bid >> 3;       // jj in 0..127
    const int bh = xcd * 8 + (jj >> 4);           // 8 bh per XCD
    const int tb = jj & 15;                       // 16 x 128-row t-tiles
    const int b = bh >> 4, h = bh & 15;
    const int i = threadIdx.x, w = i >> 6, l = i & 63;
    const int c = l & 15, g = l >> 4;

    const unsigned short* Qb  = Qp  + (size_t)bh * 2048 * 64;
    const unsigned short* Kb  = Kp  + (size_t)bh * 2048 * 64;
    const unsigned short* VTb = VTp + (size_t)bh * 64 * 2048;

    const int twave = tb * 128 + w * 32;
    const int tA = twave + c, tB = twave + 16 + c;

    // not-all-true bits for this 128-row region (wave-uniform, to SGPR)
    const unsigned notall = __builtin_amdgcn_readfirstlane(flagsW[b * 16 + tb]);

    // Q as B-operand (K32): lane holds Q[t][dk = kq*32+g*8+j]
    bf16x8 qfA[2], qfB[2];
    #pragma unroll
    for (int kq = 0; kq < 2; ++kq) {
        qfA[kq] = *(const bf16x8*)(Qb + (size_t)tA * 64 + kq * 32 + g * 8);
        qfB[kq] = *(const bf16x8*)(Qb + (size_t)tB * 64 + kq * 32 + g * 8);
    }

    f32x4 oA[4] = {}, oB[4] = {};   // O^T accum: v = vm*16+g*4+r
    f32x4 daccA = {}, daccB = {};   // denominators via ones-MFMA
    const f32x4 zf = {};            // persistent zero C-operand

    bf16x8 ones8;
    #pragma unroll
    for (int j = 0; j < 8; ++j) ones8[j] = (__bf16)1.0f;

    // kf read rows (permuted) + chunk swizzles, per sm
    int rrow[4], rswz[4];
    #pragma unroll
    for (int sm = 0; sm < 4; ++sm) {
        rrow[sm] = (sm >> 1) * 32 + (c >> 2) * 8 + (sm & 1) * 4 + (c & 3);
        rswz[sm] = (rrow[sm] ^ (rrow[sm] >> 2)) & 7;
    }
    int vswz[4];
    #pragma unroll
    for (int vm = 0; vm < 4; ++vm) {
        const int rv = vm * 16 + c;
        vswz[vm] = (rv ^ (rv >> 2)) & 7;
    }

    // staging: lane L -> LDS (row = base + L>>3, slot L&7); source chunk
    // = (L&7) ^ swz(row) so LDS slot s of row r holds global chunk s ^ swz(r).
    const int srow = l >> 3, sslot = l & 7;

    // prologue: stage tile 0 into buffer 0; running stage pointers (tile 1)
    const unsigned short* kstage[2];
    const unsigned short* vstage[2];
    #pragma unroll
    for (int u = 0; u < 2; ++u) {
        const int row = w * 16 + u * 8 + srow;
        const int ch = sslot ^ ((row ^ (row >> 2)) & 7);
        gload16(Kb + (size_t)row * 64 + ch * 8, &Kt[0][(w * 16 + u * 8) * 64]);
        gload16(VTb + (size_t)row * 2048 + ch * 8, &Vt[0][(w * 16 + u * 8) * 64]);
        kstage[u] = Kb + (size_t)(64 + row) * 64 + ch * 8;
        vstage[u] = VTb + (size_t)row * 2048 + 64 + ch * 8;
    }
    __syncthreads();

    #pragma unroll 2
    for (int it = 0; it < 32; ++it) {
        const int buf = it & 1;
        const int s0 = it * 64;

        // issue next-tile stage (lands in buf^1; drained by end-of-iter barrier)
        if (it < 31) {
            #pragma unroll
            for (int u = 0; u < 2; ++u) {
                gload16(kstage[u], &Kt[buf ^ 1][(w * 16 + u * 8) * 64]);
                gload16(vstage[u], &Vt[buf ^ 1][(w * 16 + u * 8) * 64]);
                kstage[u] += 64 * 64;
                vstage[u] += 64;
            }
        }

        // QK^T swapped, permuted rows, both groups sharing kf:
        // scX[sm][r] = S^T at s = s0 + (sm>>1)*32 + g*8 + (sm&1)*4 + r
        f32x4 scA[4], scB[4];
        __builtin_amdgcn_s_setprio(1);
        #pragma unroll
        for (int sm = 0; sm < 4; ++sm) {
            #pragma unroll
            for (int kq = 0; kq < 2; ++kq) {
                const bf16x8 kf = *(const bf16x8*)&Kt[buf][rrow[sm] * 64 + (((kq * 4 + g) ^ rswz[sm]) * 8)];
                if (kq == 0) {
                    scA[sm] = __builtin_amdgcn_mfma_f32_16x16x32_bf16(kf, qfA[0], zf, 0, 0, 0);
                    scB[sm] = __builtin_amdgcn_mfma_f32_16x16x32_bf16(kf, qfB[0], zf, 0, 0, 0);
                } else {
                    scA[sm] = __builtin_amdgcn_mfma_f32_16x16x32_bf16(kf, qfA[1], scA[sm], 0, 0, 0);
                    scB[sm] = __builtin_amdgcn_mfma_f32_16x16x32_bf16(kf, qfB[1], scB[sm], 0, 0, 0);
                }
            }
        }
        __builtin_amdgcn_s_setprio(0);

        // mask fallback (exp2 domain), permuted s indexing (scalar-skipped)
        if (notall & (1u << it)) {
            #pragma unroll
            for (int sm = 0; sm < 4; ++sm)
                #pragma unroll
                for (int r = 0; r < 4; ++r) {
                    const int s = s0 + (sm >> 1) * 32 + g * 8 + (sm & 1) * 4 + r;
                    if (mask[(size_t)(b * 2048 + tA) * 2048 + s] == 0) scA[sm][r] += MASK_ADD;
                    if (mask[(size_t)(b * 2048 + tB) * 2048 + s] == 0) scB[sm][r] += MASK_ADD;
                }
        }

        // p = exp2(sc); pack directly into K32 PV B-fragments
        bf16x8 paA[2], paB[2];
        #pragma unroll
        for (int kv = 0; kv < 2; ++kv) {
            f32x4 a0, a1, b0, b1;
            #pragma unroll
            for (int r = 0; r < 4; ++r) {
                a0[r] = __builtin_amdgcn_exp2f(scA[kv * 2][r]);
                a1[r] = __builtin_amdgcn_exp2f(scA[kv * 2 + 1][r]);
                b0[r] = __builtin_amdgcn_exp2f(scB[kv * 2][r]);
                b1[r] = __builtin_amdgcn_exp2f(scB[kv * 2 + 1][r]);
            }
            union { struct { bf16x4 lo, hi; } hh; bf16x8 v; } ua, ub;
            ua.hh.lo = __builtin_convertvector(a0, bf16x4);
            ua.hh.hi = __builtin_convertvector(a1, bf16x4);
            ub.hh.lo = __builtin_convertvector(b0, bf16x4);
            ub.hh.hi = __builtin_convertvector(b1, bf16x4);
            paA[kv] = ua.v;
            paB[kv] = ub.v;
        }

        // PV (K32) + denominators, shared vf
        __builtin_amdgcn_s_setprio(1);
        #pragma unroll
        for (int kv = 0; kv < 2; ++kv) {
            daccA = __builtin_amdgcn_mfma_f32_16x16x32_bf16(ones8, paA[kv], daccA, 0, 0, 0);
            daccB = __builtin_amdgcn_mfma_f32_16x16x32_bf16(ones8, paB[kv], daccB, 0, 0, 0);
            #pragma unroll
            for (int vm = 0; vm < 4; ++vm) {
                const bf16x8 vf = *(const bf16x8*)&Vt[buf][(vm * 16 + c) * 64 + (((kv * 4 + g) ^ vswz[vm]) * 8)];
                oA[vm] = __builtin_amdgcn_mfma_f32_16x16x32_bf16(vf, paA[kv], oA[vm], 0, 0, 0);
                oB[vm] = __builtin_amdgcn_mfma_f32_16x16x32_bf16(vf, paB[kv], oB[vm], 0, 0, 0);
            }
        }
        __builtin_amdgcn_s_setprio(0);

        __syncthreads();  // drains vmcnt (stage) + lgkm, then barrier
    }

    const float invA = 1.0f / daccA[0];
    const float invB = 1.0f / daccB[0];

    // epilogue: attnb[(b*2048+t)*1024 + h*64 + v] = O^T[v][t] * inv
    #pragma unroll
    for (int vm = 0; vm < 4; ++vm) {
        f32x4 vA, vB;
        #pragma unroll
        for (int r = 0; r < 4; ++r) { vA[r] = oA[vm][r] * invA; vB[r] = oB[vm][r] * invB; }
        bf16x4 pA = __builtin_convertvector(vA, bf16x4);
        bf16x4 pB = __builtin_convertvector(vB, bf16x4);
        *(bf16x4*)(attnb + (size_t)(b * 2048 + tA) * 1024 + h * 64 + vm * 16 + g * 4) = pA;
        *(bf16x4*)(attnb + (size_t)(b * 2048 + tB) * 1024 + h * 64 + vm * 16 + g * 4) = pB;
    }
}

// ---------------------------------------------------------------------------
extern "C" void kernel_launch(void* const* d_in, const int* in_sizes, int n_in,
                              void* d_out, int out_size, void* d_ws, size_t ws_size,
                              hipStream_t stream) {
    const float* query = (const float*)d_in[0];
    const float* value = (const float*)d_in[1];
    const int*   mask  = (const int*)d_in[2];
    const float* Wq = (const float*)d_in[3];
    const float* bq = (const float*)d_in[4];
    const float* Wk = (const float*)d_in[5];
    const float* bk = (const float*)d_in[6];
    const float* Wv = (const float*)d_in[7];
    const float* bv = (const float*)d_in[8];
    const float* Wo = (const float*)d_in[9];
    const float* bo = (const float*)d_in[10];

    char* ws = (char*)d_ws;
    unsigned short* WqT   = (unsigned short*)(ws + ((size_t)0  << 20));  // 2 MB (x C_EXP)
    unsigned short* WkT   = (unsigned short*)(ws + ((size_t)2  << 20));  // 2 MB  } contiguous ->
    unsigned short* WvT   = (unsigned short*)(ws + ((size_t)4  << 20));  // 2 MB  } stacked KV BT
    unsigned short* WoT   = (unsigned short*)(ws + ((size_t)6  << 20));  // 2 MB
    unsigned*       flagsW= (unsigned*)      (ws + ((size_t)8  << 20));  // 256 B (bitwords)
    unsigned short* CONV  = (unsigned short*)(ws + ((size_t)9  << 20));  // 16 MB (Vbf16 -> Qbf16 -> attnb)
    unsigned short* Qp    = (unsigned short*)(ws + ((size_t)25 << 20));  // 16 MB (pre-scaled Q)
    unsigned short* Kp    = (unsigned short*)(ws + ((size_t)41 << 20));  // 16 MB
    unsigned short* VTp   = (unsigned short*)(ws + ((size_t)57 << 20));  // 16 MB ([bh][v][s])

    const int n8 = 8192 * 1024 / 8;

    hipMemsetAsync(flagsW, 0, 64 * sizeof(unsigned), stream);

    // value -> bf16; merged K|V projection consumes it (BT = WkT||WvT stacked)
    cvt_kernel<<<2048, 256, 0, stream>>>(value, CONV, n8);
    wtrans_kernel<<<dim3(16, 16, 4), 256, 0, stream>>>(Wq, Wk, Wv, Wo, WqT, WkT, WvT, WoT);
    maskflag_kernel<<<2048, 256, 0, stream>>>(mask, flagsW);
    mm_kernel<3, 16><<<1024, 256, 0, stream>>>(CONV, WkT, bk, bv, 1.0f, Kp, VTp);

    // query -> bf16 (reuses CONV; value-bf16 dead now)
    cvt_kernel<<<2048, 256, 0, stream>>>(query, CONV, n8);
    mm_kernel<0, 8><<<512, 256, 0, stream>>>(CONV, WqT, bq, bq, C_EXP, Qp, nullptr);

    // attention writes attnb into CONV (query-bf16 dead now)
    attn_kernel<<<1024, 256, 0, stream>>>(Qp, Kp, VTp, mask, flagsW, CONV);

    mm_kernel<2, 8><<<512, 256, 0, stream>>>(CONV, WoT, bo, bo, 1.0f, d_out, nullptr);
}

// Round 13
// 207.018 us; speedup vs baseline: 2.0285x; 1.0267x over previous
//
#include <hip/hip_runtime.h>

typedef __bf16 bf16x8 __attribute__((ext_vector_type(8)));
typedef __bf16 bf16x4 __attribute__((ext_vector_type(4)));
typedef float  f32x4  __attribute__((ext_vector_type(4)));
typedef int    i32x4  __attribute__((ext_vector_type(4)));

typedef __attribute__((address_space(1))) unsigned int as1_u32;
typedef __attribute__((address_space(3))) unsigned int as3_u32;

#define DEVI __device__ __forceinline__

DEVI unsigned short f2bf(float f) {
    union { float f; unsigned u; } v; v.f = f;
    unsigned r = (v.u + 0x7fffu + ((v.u >> 16) & 1u)) >> 16;
    return (unsigned short)r;
}

// direct global->LDS 16B: lane L's 16B lands at ldsbase + L*16
DEVI void gload16(const void* g, void* l) {
    __builtin_amdgcn_global_load_lds((const as1_u32*)g, (as3_u32*)l, 16, 0, 0);
}

// softmax(x/8) = exp2(x * 0.125 * log2(e)); scale folded into Q projection.
#define C_EXP 0.18033688011112042f
// -10000 * log2(e)
#define MASK_ADD (-14426.950408889634f)

// ---------------------------------------------------------------------------
// Transpose 4x (1024x1024) f32 -> bf16: WT[n][k] = W[k][n]*scale, z selects.
// ---------------------------------------------------------------------------
__global__ __launch_bounds__(256) void wtrans_kernel(const float* __restrict__ W0,
                                                     const float* __restrict__ W1,
                                                     const float* __restrict__ W2,
                                                     const float* __restrict__ W3,
                                                     unsigned short* __restrict__ T0,
                                                     unsigned short* __restrict__ T1,
                                                     unsigned short* __restrict__ T2,
                                                     unsigned short* __restrict__ T3) {
    __shared__ float tile[64][65];
    const float* W;
    unsigned short* WT;
    float scale = 1.0f;
    switch (blockIdx.z) {
        case 0:  W = W0; WT = T0; scale = C_EXP; break;
        case 1:  W = W1; WT = T1; break;
        case 2:  W = W2; WT = T2; break;
        default: W = W3; WT = T3; break;
    }
    const int k0 = blockIdx.x * 64, n0 = blockIdx.y * 64;
    const int i = threadIdx.x;
    const int c4 = (i & 15) * 4, rbase = i >> 4;
    for (int rr = 0; rr < 4; ++rr) {
        const int kl = rbase + rr * 16;
        const float4 v = *(const float4*)(W + (size_t)(k0 + kl) * 1024 + n0 + c4);
        tile[kl][c4 + 0] = v.x; tile[kl][c4 + 1] = v.y;
        tile[kl][c4 + 2] = v.z; tile[kl][c4 + 3] = v.w;
    }
    __syncthreads();
    for (int rr = 0; rr < 4; ++rr) {
        const int nl = rbase + rr * 16;
        ushort4 o;
        o.x = f2bf(tile[c4 + 0][nl] * scale); o.y = f2bf(tile[c4 + 1][nl] * scale);
        o.z = f2bf(tile[c4 + 2][nl] * scale); o.w = f2bf(tile[c4 + 3][nl] * scale);
        *(ushort4*)(WT + (size_t)(n0 + nl) * 1024 + k0 + c4) = o;
    }
}

// ---------------------------------------------------------------------------
// Mask not-all-true bits: word[(b*16+tb128)] bit si set if any zero in the
// (b, 128-row t-tile, 64-col s-tile). mask is int32. flagsW pre-zeroed.
// ---------------------------------------------------------------------------
__global__ __launch_bounds__(256) void maskflag_kernel(const int* __restrict__ mask,
                                                       unsigned* __restrict__ flagsW) {
    const int bid = blockIdx.x;
    const int b = bid >> 9, rem = bid & 511;
    const int tb = rem >> 5, si = rem & 31;
    const int i = threadIdx.x;
    const int t = tb * 128 + (i >> 1);
    const int s = si * 64 + (i & 1) * 32;
    const uint4* p = (const uint4*)(mask + ((size_t)(b * 2048 + t)) * 2048 + s);
    int ok = 1;
    #pragma unroll
    for (int u = 0; u < 8; ++u) {
        const uint4 a = p[u];
        ok &= (a.x != 0) & (a.y != 0) & (a.z != 0) & (a.w != 0);
    }
    int all = __syncthreads_and(ok);
    if (i == 0 && !all) atomicOr(&flagsW[b * 16 + tb], 1u << si);
}

// ---------------------------------------------------------------------------
// Unified bf16 GEMM: C[m,n] = A[m,:] . BT[n,:] + bias[n]*bscale
// 128x128 tile, BK=64, DOUBLE-BUFFERED staging (R10 structure - proven best;
// R12's counted-vmcnt 2-phase was -8us, reverted per catalog regime gate).
// AF32=1: A is f32, fused convert: reg-stage (2x float4 -> cvt_pk -> one
//   ds_write_b128), loads for tile it+1 issued BEFORE the MFMA phase,
//   cvt+write AFTER it (T14 split) - kills the separate cvt kernel pass.
//   ds_write conflict-free: 8 consecutive lanes = 8 slots of one row = 32 banks.
// AF32=0: A staged via global_load_lds (bf16 input).
// XOR chunk-swizzle swz8(r) = (r^(r>>2))&7 on stage source and reads.
// XCD-swizzled 1D grid: NB n-blocks per m-panel land on one XCD.
// MODE 0: bf16 scatter [b][h][t][c]        (Q)
// MODE 2: f32 linear [m][n]                (output)
// MODE 3: merged K|V: n<1024 -> K scatter; n>=1024 -> V^T scatter.
// ---------------------------------------------------------------------------
template <int MODE, int NB, int AF32>
__global__ __launch_bounds__(256) void mm_kernel(const void* __restrict__ Av,
                                                 const unsigned short* __restrict__ BT,
                                                 const float* __restrict__ biasK,
                                                 const float* __restrict__ biasV,
                                                 float bscale,
                                                 void* __restrict__ OvK,
                                                 void* __restrict__ OvV) {
    __shared__ __align__(16) unsigned short Ab[2][128 * 64];
    __shared__ __align__(16) unsigned short Bb[2][128 * 64];
    const int bid = blockIdx.x;
    const int xcd = bid & 7, jj = bid >> 3;
    const int n0 = (jj % NB) * 128;
    const int m0 = ((jj / NB) * 8 + xcd) * 128;
    const int i = threadIdx.x, w = i >> 6, l = i & 63;
    const int wm = w >> 1, wn = w & 1;
    const int c = l & 15, g = l >> 4;
    const int srow = l >> 3, sslot = l & 7;

    f32x4 acc[4][4] = {};

    // staging geometry: step u covers rows w*32+u*8 .. +8; lane covers
    // (row = base+srow, slot = sslot). LDS slot s of row r holds global
    // chunk s ^ swz8(r), swz8(r) = (r^(r>>2))&7.
    int arow[4];                       // global row per step (A side)
    int achunk[4];                     // source chunk per step
    const unsigned short* Bs[4];
    unsigned lofs[4];                  // LDS elem offset of (row) per step
    #pragma unroll
    for (int u = 0; u < 4; ++u) {
        const int rl = w * 32 + u * 8 + srow;
        const int ch = sslot ^ ((rl ^ (rl >> 2)) & 7);
        arow[u] = rl;
        achunk[u] = ch;
        Bs[u] = BT + (size_t)(n0 + rl) * 1024 + ch * 8;
        lofs[u] = (unsigned)(rl * 64);
    }

    const float* Af = (const float*)Av;
    const unsigned short* Ab16 = (const unsigned short*)Av;

    // read-side row swizzles
    int rsA[4], rsB[4];
    #pragma unroll
    for (int f = 0; f < 4; ++f) {
        const int ra = wm * 64 + f * 16 + c;
        const int rb = wn * 64 + f * 16 + c;
        rsA[f] = (ra ^ (ra >> 2)) & 7;
        rsB[f] = (rb ^ (rb >> 2)) & 7;
    }

    // prologue: stage k-tile 0 into buffer 0
    #pragma unroll
    for (int u = 0; u < 4; ++u)
        gload16(Bs[u], &Bb[0][(w * 32 + u * 8) * 64]);
    if (AF32) {
        #pragma unroll
        for (int u = 0; u < 4; ++u) {
            const float* src = Af + (size_t)(m0 + arow[u]) * 1024 + achunk[u] * 8;
            const f32x4 lo = *(const f32x4*)(src);
            const f32x4 hi = *(const f32x4*)(src + 4);
            union { struct { bf16x4 lo, hi; } h; i32x4 q; } uu;
            uu.h.lo = __builtin_convertvector(lo, bf16x4);
            uu.h.hi = __builtin_convertvector(hi, bf16x4);
            *(i32x4*)&Ab[0][lofs[u] + sslot * 8] = uu.q;
        }
    } else {
        #pragma unroll
        for (int u = 0; u < 4; ++u)
            gload16(Ab16 + (size_t)(m0 + arow[u]) * 1024 + achunk[u] * 8,
                    &Ab[0][(w * 32 + u * 8) * 64]);
    }
    __syncthreads();

    #pragma unroll 2
    for (int it = 0; it < 16; ++it) {
        const int buf = it & 1;
        f32x4 areg[4][2];
        // issue next-tile loads before compute (latency hides under MFMA)
        if (it < 15) {
            #pragma unroll
            for (int u = 0; u < 4; ++u)
                gload16(Bs[u] + (it + 1) * 64, &Bb[buf ^ 1][(w * 32 + u * 8) * 64]);
            if (AF32) {
                #pragma unroll
                for (int u = 0; u < 4; ++u) {
                    const float* src = Af + (size_t)(m0 + arow[u]) * 1024 + (it + 1) * 64 + achunk[u] * 8;
                    areg[u][0] = *(const f32x4*)(src);
                    areg[u][1] = *(const f32x4*)(src + 4);
                }
            } else {
                #pragma unroll
                for (int u = 0; u < 4; ++u)
                    gload16(Ab16 + (size_t)(m0 + arow[u]) * 1024 + (it + 1) * 64 + achunk[u] * 8,
                            &Ab[buf ^ 1][(w * 32 + u * 8) * 64]);
            }
        }

        bf16x8 af[4][2], bfr[4][2];
        #pragma unroll
        for (int f = 0; f < 4; ++f)
            #pragma unroll
            for (int kk = 0; kk < 2; ++kk) {
                af[f][kk]  = *(const bf16x8*)&Ab[buf][(wm * 64 + f * 16 + c) * 64 + (((kk * 4 + g) ^ rsA[f]) * 8)];
                bfr[f][kk] = *(const bf16x8*)&Bb[buf][(wn * 64 + f * 16 + c) * 64 + (((kk * 4 + g) ^ rsB[f]) * 8)];
            }
        __builtin_amdgcn_s_setprio(1);
        #pragma unroll
        for (int kk = 0; kk < 2; ++kk)
            #pragma unroll
            for (int mf = 0; mf < 4; ++mf)
                #pragma unroll
                for (int nf = 0; nf < 4; ++nf)
                    acc[mf][nf] = __builtin_amdgcn_mfma_f32_16x16x32_bf16(af[mf][kk], bfr[nf][kk], acc[mf][nf], 0, 0, 0);
        __builtin_amdgcn_s_setprio(0);

        // write staged A (safe: buf^1 reads finished at end of iter it-1)
        if (AF32 && it < 15) {
            #pragma unroll
            for (int u = 0; u < 4; ++u) {
                union { struct { bf16x4 lo, hi; } h; i32x4 q; } uu;
                uu.h.lo = __builtin_convertvector(areg[u][0], bf16x4);
                uu.h.hi = __builtin_convertvector(areg[u][1], bf16x4);
                *(i32x4*)&Ab[buf ^ 1][lofs[u] + sslot * 8] = uu.q;
            }
        }
        __syncthreads();  // drains vmcnt (B stage) + lgkm (A writes, ds_reads)
    }

    #pragma unroll
    for (int nf = 0; nf < 4; ++nf) {
        const int n = n0 + wn * 64 + nf * 16 + c;
        if (MODE == 0 || (MODE == 3 && n0 < 1024)) {
            const float bv = biasK[n] * bscale;
            const int h = n >> 6, cc = n & 63;
            unsigned short* O = (unsigned short*)OvK;
            #pragma unroll
            for (int mf = 0; mf < 4; ++mf) {
                const int mbase = m0 + wm * 64 + mf * 16 + g * 4;
                const int b = mbase >> 11, t = mbase & 2047;
                #pragma unroll
                for (int r = 0; r < 4; ++r)
                    O[(((size_t)(b * 16 + h)) * 2048 + t + r) * 64 + cc] = f2bf(acc[mf][nf][r] + bv);
            }
        } else if (MODE == 3) {
            const int nn = n - 1024;
            const float bv = biasV[nn];
            const int h = nn >> 6, cc = nn & 63;
            unsigned short* O = (unsigned short*)OvV;
            #pragma unroll
            for (int mf = 0; mf < 4; ++mf) {
                const int mbase = m0 + wm * 64 + mf * 16 + g * 4;
                const int b = mbase >> 11, t = mbase & 2047;
                f32x4 v;
                #pragma unroll
                for (int r = 0; r < 4; ++r) v[r] = acc[mf][nf][r] + bv;
                bf16x4 pv = __builtin_convertvector(v, bf16x4);
                *(bf16x4*)(O + (((size_t)(b * 16 + h)) * 64 + cc) * 2048 + t) = pv;
            }
        } else {
            const float bv = biasK[n] * bscale;
            float* O = (float*)OvK;
            #pragma unroll
            for (int mf = 0; mf < 4; ++mf) {
                const int mbase = m0 + wm * 64 + mf * 16 + g * 4;
                #pragma unroll
                for (int r = 0; r < 4; ++r)
                    O[(size_t)(mbase + r) * 1024 + n] = acc[mf][nf][r] + bv;
            }
        }
    }
}

// ---------------------------------------------------------------------------
// Flash attention, swapped QK^T with PERMUTED K rows (P in registers, K32 PV).
// Each wave handles TWO 16-row t-groups (block = 128 Q rows, grid = 1024 =
// 4 blocks/CU; LDS 4x32KB = 128KB). Shared kf/vf LDS reads feed both groups.
// Flags bitword granularity = one block. setprio around MFMA clusters.
// XCD swizzle: each XCD owns 8 bh x 16 tb (K/V 4MB = L2-resident).
// ---------------------------------------------------------------------------
__global__ __launch_bounds__(256, 4) void attn_kernel(const unsigned short* __restrict__ Qp,
                                                      const unsigned short* __restrict__ Kp,
                                                      const unsigned short* __restrict__ VTp,
                                                      const int* __restrict__ mask,
                                                      const unsigned* __restrict__ flagsW,
                                                      unsigned short* __restrict__ attnb) {
    __shared__ __align__(16) unsigned short Kt[2][64 * 64];  // [s][dk], swizzled chunks
    __shared__ __align__(16) unsigned short Vt[2][64 * 64];  // [v][s],  swizzled chunks

    const int bid = blockIdx.x;
    const int xcd = bid & 7, jj = bid >> 3;       // jj in 0..127
    const int bh = xcd * 8 + (jj >> 4);           // 8 bh per XCD
    const int tb = jj & 15;                       // 16 x 128-row t-tiles
    const int b = bh >> 4, h = bh & 15;
    const int i = threadIdx.x, w = i >> 6, l = i & 63;
    const int c = l & 15, g = l >> 4;

    const unsigned short* Qb  = Qp  + (size_t)bh * 2048 * 64;
    const unsigned short* Kb  = Kp  + (size_t)bh * 2048 * 64;
    const unsigned short* VTb = VTp + (size_t)bh * 64 * 2048;

    const int twave = tb * 128 + w * 32;
    const int tA = twave + c, tB = twave + 16 + c;

    // not-all-true bits for this 128-row region (wave-uniform, to SGPR)
    const unsigned notall = __builtin_amdgcn_readfirstlane(flagsW[b * 16 + tb]);

    // Q as B-operand (K32): lane holds Q[t][dk = kq*32+g*8+j]
    bf16x8 qfA[2], qfB[2];
    #pragma unroll
    for (int kq = 0; kq < 2; ++kq) {
        qfA[kq] = *(const bf16x8*)(Qb + (size_t)tA * 64 + kq * 32 + g * 8);
        qfB[kq] = *(const bf16x8*)(Qb + (size_t)tB * 64 + kq * 32 + g * 8);
    }

    f32x4 oA[4] = {}, oB[4] = {};   // O^T accum: v = vm*16+g*4+r
    f32x4 daccA = {}, daccB = {};   // denominators via ones-MFMA
    const f32x4 zf = {};            // persistent zero C-operand

    bf16x8 ones8;
    #pragma unroll
    for (int j = 0; j < 8; ++j) ones8[j] = (__bf16)1.0f;

    // kf read rows (permuted) + chunk swizzles, per sm
    int rrow[4], rswz[4];
    #pragma unroll
    for (int sm = 0; sm < 4; ++sm) {
        rrow[sm] = (sm >> 1) * 32 + (c >> 2) * 8 + (sm & 1) * 4 + (c & 3);
        rswz[sm] = (rrow[sm] ^ (rrow[sm] >> 2)) & 7;
    }
    int vswz[4];
    #pragma unroll
    for (int vm = 0; vm < 4; ++vm) {
        const int rv = vm * 16 + c;
        vswz[vm] = (rv ^ (rv >> 2)) & 7;
    }

    // staging: lane L -> LDS (row = base + L>>3, slot L&7); source chunk
    // = (L&7) ^ swz(row) so LDS slot s of row r holds global chunk s ^ swz(r).
    const int srow = l >> 3, sslot = l & 7;

    // prologue: stage tile 0 into buffer 0; running stage pointers (tile 1)
    const unsigned short* kstage[2];
    const unsigned short* vstage[2];
    #pragma unroll
    for (int u = 0; u < 2; ++u) {
        const int row = w * 16 + u * 8 + srow;
        const int ch = sslot ^ ((row ^ (row >> 2)) & 7);
        gload16(Kb + (size_t)row * 64 + ch * 8, &Kt[0][(w * 16 + u * 8) * 64]);
        gload16(VTb + (size_t)row * 2048 + ch * 8, &Vt[0][(w * 16 + u * 8) * 64]);
        kstage[u] = Kb + (size_t)(64 + row) * 64 + ch * 8;
        vstage[u] = VTb + (size_t)row * 2048 + 64 + ch * 8;
    }
    __syncthreads();

    #pragma unroll 2
    for (int it = 0; it < 32; ++it) {
        const int buf = it & 1;
        const int s0 = it * 64;

        // issue next-tile stage (lands in buf^1; drained by end-of-iter barrier)
        if (it < 31) {
            #pragma unroll
            for (int u = 0; u < 2; ++u) {
                gload16(kstage[u], &Kt[buf ^ 1][(w * 16 + u * 8) * 64]);
                gload16(vstage[u], &Vt[buf ^ 1][(w * 16 + u * 8) * 64]);
                kstage[u] += 64 * 64;
                vstage[u] += 64;
            }
        }

        // QK^T swapped, permuted rows, both groups sharing kf:
        // scX[sm][r] = S^T at s = s0 + (sm>>1)*32 + g*8 + (sm&1)*4 + r
        f32x4 scA[4], scB[4];
        __builtin_amdgcn_s_setprio(1);
        #pragma unroll
        for (int sm = 0; sm < 4; ++sm) {
            #pragma unroll
            for (int kq = 0; kq < 2; ++kq) {
                const bf16x8 kf = *(const bf16x8*)&Kt[buf][rrow[sm] * 64 + (((kq * 4 + g) ^ rswz[sm]) * 8)];
                if (kq == 0) {
                    scA[sm] = __builtin_amdgcn_mfma_f32_16x16x32_bf16(kf, qfA[0], zf, 0, 0, 0);
                    scB[sm] = __builtin_amdgcn_mfma_f32_16x16x32_bf16(kf, qfB[0], zf, 0, 0, 0);
                } else {
                    scA[sm] = __builtin_amdgcn_mfma_f32_16x16x32_bf16(kf, qfA[1], scA[sm], 0, 0, 0);
                    scB[sm] = __builtin_amdgcn_mfma_f32_16x16x32_bf16(kf, qfB[1], scB[sm], 0, 0, 0);
                }
            }
        }
        __builtin_amdgcn_s_setprio(0);

        // mask fallback (exp2 domain), permuted s indexing (scalar-skipped)
        if (notall & (1u << it)) {
            #pragma unroll
            for (int sm = 0; sm < 4; ++sm)
                #pragma unroll
                for (int r = 0; r < 4; ++r) {
                    const int s = s0 + (sm >> 1) * 32 + g * 8 + (sm & 1) * 4 + r;
                    if (mask[(size_t)(b * 2048 + tA) * 2048 + s] == 0) scA[sm][r] += MASK_ADD;
                    if (mask[(size_t)(b * 2048 + tB) * 2048 + s] == 0) scB[sm][r] += MASK_ADD;
                }
        }

        // p = exp2(sc); pack directly into K32 PV B-fragments
        bf16x8 paA[2], paB[2];
        #pragma unroll
        for (int kv = 0; kv < 2; ++kv) {
            f32x4 a0, a1, b0, b1;
            #pragma unroll
            for (int r = 0; r < 4; ++r) {
                a0[r] = __builtin_amdgcn_exp2f(scA[kv * 2][r]);
                a1[r] = __builtin_amdgcn_exp2f(scA[kv * 2 + 1][r]);
                b0[r] = __builtin_amdgcn_exp2f(scB[kv * 2][r]);
                b1[r] = __builtin_amdgcn_exp2f(scB[kv * 2 + 1][r]);
            }
            union { struct { bf16x4 lo, hi; } hh; bf16x8 v; } ua, ub;
            ua.hh.lo = __builtin_convertvector(a0, bf16x4);
            ua.hh.hi = __builtin_convertvector(a1, bf16x4);
            ub.hh.lo = __builtin_convertvector(b0, bf16x4);
            ub.hh.hi = __builtin_convertvector(b1, bf16x4);
            paA[kv] = ua.v;
            paB[kv] = ub.v;
        }

        // PV (K32) + denominators, shared vf
        __builtin_amdgcn_s_setprio(1);
        #pragma unroll
        for (int kv = 0; kv < 2; ++kv) {
            daccA = __builtin_amdgcn_mfma_f32_16x16x32_bf16(ones8, paA[kv], daccA, 0, 0, 0);
            daccB = __builtin_amdgcn_mfma_f32_16x16x32_bf16(ones8, paB[kv], daccB, 0, 0, 0);
            #pragma unroll
            for (int vm = 0; vm < 4; ++vm) {
                const bf16x8 vf = *(const bf16x8*)&Vt[buf][(vm * 16 + c) * 64 + (((kv * 4 + g) ^ vswz[vm]) * 8)];
                oA[vm] = __builtin_amdgcn_mfma_f32_16x16x32_bf16(vf, paA[kv], oA[vm], 0, 0, 0);
                oB[vm] = __builtin_amdgcn_mfma_f32_16x16x32_bf16(vf, paB[kv], oB[vm], 0, 0, 0);
            }
        }
        __builtin_amdgcn_s_setprio(0);

        __syncthreads();  // drains vmcnt (stage) + lgkm, then barrier
    }

    const float invA = 1.0f / daccA[0];
    const float invB = 1.0f / daccB[0];

    // epilogue: attnb[(b*2048+t)*1024 + h*64 + v] = O^T[v][t] * inv
    #pragma unroll
    for (int vm = 0; vm < 4; ++vm) {
        f32x4 vA, vB;
        #pragma unroll
        for (int r = 0; r < 4; ++r) { vA[r] = oA[vm][r] * invA; vB[r] = oB[vm][r] * invB; }
        bf16x4 pA = __builtin_convertvector(vA, bf16x4);
        bf16x4 pB = __builtin_convertvector(vB, bf16x4);
        *(bf16x4*)(attnb + (size_t)(b * 2048 + tA) * 1024 + h * 64 + vm * 16 + g * 4) = pA;
        *(bf16x4*)(attnb + (size_t)(b * 2048 + tB) * 1024 + h * 64 + vm * 16 + g * 4) = pB;
    }
}

// ---------------------------------------------------------------------------
extern "C" void kernel_launch(void* const* d_in, const int* in_sizes, int n_in,
                              void* d_out, int out_size, void* d_ws, size_t ws_size,
                              hipStream_t stream) {
    const float* query = (const float*)d_in[0];
    const float* value = (const float*)d_in[1];
    const int*   mask  = (const int*)d_in[2];
    const float* Wq = (const float*)d_in[3];
    const float* bq = (const float*)d_in[4];
    const float* Wk = (const float*)d_in[5];
    const float* bk = (const float*)d_in[6];
    const float* Wv = (const float*)d_in[7];
    const float* bv = (const float*)d_in[8];
    const float* Wo = (const float*)d_in[9];
    const float* bo = (const float*)d_in[10];

    char* ws = (char*)d_ws;
    unsigned short* WqT   = (unsigned short*)(ws + ((size_t)0  << 20));  // 2 MB (x C_EXP)
    unsigned short* WkT   = (unsigned short*)(ws + ((size_t)2  << 20));  // 2 MB  } contiguous ->
    unsigned short* WvT   = (unsigned short*)(ws + ((size_t)4  << 20));  // 2 MB  } stacked KV BT
    unsigned short* WoT   = (unsigned short*)(ws + ((size_t)6  << 20));  // 2 MB
    unsigned*       flagsW= (unsigned*)      (ws + ((size_t)8  << 20));  // 256 B (bitwords)
    unsigned short* attnb = (unsigned short*)(ws + ((size_t)9  << 20));  // 16 MB
    unsigned short* Qp    = (unsigned short*)(ws + ((size_t)25 << 20));  // 16 MB (pre-scaled Q)
    unsigned short* Kp    = (unsigned short*)(ws + ((size_t)41 << 20));  // 16 MB
    unsigned short* VTp   = (unsigned short*)(ws + ((size_t)57 << 20));  // 16 MB ([bh][v][s])

    hipMemsetAsync(flagsW, 0, 64 * sizeof(unsigned), stream);

    wtrans_kernel<<<dim3(16, 16, 4), 256, 0, stream>>>(Wq, Wk, Wv, Wo, WqT, WkT, WvT, WoT);
    maskflag_kernel<<<2048, 256, 0, stream>>>(mask, flagsW);

    // fused f32->bf16 A-staging: K|V projection reads value f32 directly
    mm_kernel<3, 16, 1><<<1024, 256, 0, stream>>>(value, WkT, bk, bv, 1.0f, Kp, VTp);
    // Q projection reads query f32 directly (scale folded)
    mm_kernel<0, 8, 1><<<512, 256, 0, stream>>>(query, WqT, bq, bq, C_EXP, Qp, nullptr);

    attn_kernel<<<1024, 256, 0, stream>>>(Qp, Kp, VTp, mask, flagsW, attnb);

    mm_kernel<2, 8, 0><<<512, 256, 0, stream>>>(attnb, WoT, bo, bo, 1.0f, d_out, nullptr);
}

// Round 14
// 202.238 us; speedup vs baseline: 2.0765x; 1.0236x over previous
//
#include <hip/hip_runtime.h>

typedef __bf16 bf16x8 __attribute__((ext_vector_type(8)));
typedef __bf16 bf16x4 __attribute__((ext_vector_type(4)));
typedef float  f32x4  __attribute__((ext_vector_type(4)));
typedef int    i32x4  __attribute__((ext_vector_type(4)));

typedef __attribute__((address_space(1))) unsigned int as1_u32;
typedef __attribute__((address_space(3))) unsigned int as3_u32;

#define DEVI __device__ __forceinline__

DEVI unsigned short f2bf(float f) {
    union { float f; unsigned u; } v; v.f = f;
    unsigned r = (v.u + 0x7fffu + ((v.u >> 16) & 1u)) >> 16;
    return (unsigned short)r;
}

// direct global->LDS 16B: lane L's 16B lands at ldsbase + L*16
DEVI void gload16(const void* g, void* l) {
    __builtin_amdgcn_global_load_lds((const as1_u32*)g, (as3_u32*)l, 16, 0, 0);
}

// softmax(x/8) = exp2(x * 0.125 * log2(e)); scale folded into Q projection.
#define C_EXP 0.18033688011112042f
// -10000 * log2(e)
#define MASK_ADD (-14426.950408889634f)

// ---------------------------------------------------------------------------
// Dual f32 -> bf16 bulk convert: in0 -> out0, in1 -> out1 (n8 chunks each).
// One launch converts both value and query (saves a launch gap vs 2x cvt).
// ---------------------------------------------------------------------------
__global__ __launch_bounds__(256) void cvt2_kernel(const float* __restrict__ in0,
                                                   unsigned short* __restrict__ out0,
                                                   const float* __restrict__ in1,
                                                   unsigned short* __restrict__ out1,
                                                   int n8) {
    const int stride = gridDim.x * 256;
    const int total = 2 * n8;
    for (int idx = blockIdx.x * 256 + threadIdx.x; idx < total; idx += stride) {
        const int sel = idx >= n8;
        const int j = sel ? idx - n8 : idx;
        const float* in = sel ? in1 : in0;
        unsigned short* out = sel ? out1 : out0;
        const f32x4 a = *(const f32x4*)(in + (size_t)j * 8);
        const f32x4 b = *(const f32x4*)(in + (size_t)j * 8 + 4);
        union { bf16x4 v[2]; i32x4 q; } u;
        u.v[0] = __builtin_convertvector(a, bf16x4);
        u.v[1] = __builtin_convertvector(b, bf16x4);
        *(i32x4*)(out + (size_t)j * 8) = u.q;
    }
}

// ---------------------------------------------------------------------------
// Transpose 4x (1024x1024) f32 -> bf16: WT[n][k] = W[k][n]*scale, z selects.
// ---------------------------------------------------------------------------
__global__ __launch_bounds__(256) void wtrans_kernel(const float* __restrict__ W0,
                                                     const float* __restrict__ W1,
                                                     const float* __restrict__ W2,
                                                     const float* __restrict__ W3,
                                                     unsigned short* __restrict__ T0,
                                                     unsigned short* __restrict__ T1,
                                                     unsigned short* __restrict__ T2,
                                                     unsigned short* __restrict__ T3) {
    __shared__ float tile[64][65];
    const float* W;
    unsigned short* WT;
    float scale = 1.0f;
    switch (blockIdx.z) {
        case 0:  W = W0; WT = T0; scale = C_EXP; break;
        case 1:  W = W1; WT = T1; break;
        case 2:  W = W2; WT = T2; break;
        default: W = W3; WT = T3; break;
    }
    const int k0 = blockIdx.x * 64, n0 = blockIdx.y * 64;
    const int i = threadIdx.x;
    const int c4 = (i & 15) * 4, rbase = i >> 4;
    for (int rr = 0; rr < 4; ++rr) {
        const int kl = rbase + rr * 16;
        const float4 v = *(const float4*)(W + (size_t)(k0 + kl) * 1024 + n0 + c4);
        tile[kl][c4 + 0] = v.x; tile[kl][c4 + 1] = v.y;
        tile[kl][c4 + 2] = v.z; tile[kl][c4 + 3] = v.w;
    }
    __syncthreads();
    for (int rr = 0; rr < 4; ++rr) {
        const int nl = rbase + rr * 16;
        ushort4 o;
        o.x = f2bf(tile[c4 + 0][nl] * scale); o.y = f2bf(tile[c4 + 1][nl] * scale);
        o.z = f2bf(tile[c4 + 2][nl] * scale); o.w = f2bf(tile[c4 + 3][nl] * scale);
        *(ushort4*)(WT + (size_t)(n0 + nl) * 1024 + k0 + c4) = o;
    }
}

// ---------------------------------------------------------------------------
// Mask not-all-true bits: word[(b*16+tb128)] bit si set if any zero in the
// (b, 128-row t-tile, 64-col s-tile). mask is int32. flagsW pre-zeroed.
// ---------------------------------------------------------------------------
__global__ __launch_bounds__(256) void maskflag_kernel(const int* __restrict__ mask,
                                                       unsigned* __restrict__ flagsW) {
    const int bid = blockIdx.x;
    const int b = bid >> 9, rem = bid & 511;
    const int tb = rem >> 5, si = rem & 31;
    const int i = threadIdx.x;
    const int t = tb * 128 + (i >> 1);
    const int s = si * 64 + (i & 1) * 32;
    const uint4* p = (const uint4*)(mask + ((size_t)(b * 2048 + t)) * 2048 + s);
    int ok = 1;
    #pragma unroll
    for (int u = 0; u < 8; ++u) {
        const uint4 a = p[u];
        ok &= (a.x != 0) & (a.y != 0) & (a.z != 0) & (a.w != 0);
    }
    int all = __syncthreads_and(ok);
    if (i == 0 && !all) atomicOr(&flagsW[b * 16 + tb], 1u << si);
}

// ---------------------------------------------------------------------------
// Unified bf16 GEMM (R10 structure, proven best): C[m,n] = A . BT^T + bias
// 128x128 tile, BK=64, DOUBLE-BUFFERED global_load_lds staging (stage k+1
// issued before compute of k -> latency hidden under 32 MFMA + 16 ds_read).
// XOR chunk-swizzle (swz8(r) = (r^(r>>2))&7) on stage source and reads.
// XCD-swizzled 1D grid: NB n-blocks per m-panel land on one XCD.
// MODE 0: bf16 scatter [b][h][t][c]        (Q)
// MODE 2: f32 linear [m][n]                (output)
// MODE 3: merged K|V: n<1024 -> K scatter; n>=1024 -> V^T scatter.
// ---------------------------------------------------------------------------
template <int MODE, int NB>
__global__ __launch_bounds__(256) void mm_kernel(const unsigned short* __restrict__ A,
                                                 const unsigned short* __restrict__ BT,
                                                 const float* __restrict__ biasK,
                                                 const float* __restrict__ biasV,
                                                 float bscale,
                                                 void* __restrict__ OvK,
                                                 void* __restrict__ OvV) {
    __shared__ __align__(16) unsigned short Ab[2][128 * 64];
    __shared__ __align__(16) unsigned short Bb[2][128 * 64];
    const int bid = blockIdx.x;
    const int xcd = bid & 7, jj = bid >> 3;
    const int n0 = (jj % NB) * 128;
    const int m0 = ((jj / NB) * 8 + xcd) * 128;
    const int i = threadIdx.x, w = i >> 6, l = i & 63;
    const int wm = w >> 1, wn = w & 1;
    const int c = l & 15, g = l >> 4;
    const int srow = l >> 3, sslot = l & 7;

    f32x4 acc[4][4] = {};

    // staging sources: wave w stages rows [w*32, w*32+32), 8 rows per gload.
    // LDS slot s of row r holds global chunk s ^ swz8(r), swz8(r)=(r^(r>>2))&7.
    const unsigned short* As[4];
    const unsigned short* Bs[4];
    unsigned lofs[4];
    #pragma unroll
    for (int u = 0; u < 4; ++u) {
        const int rl = w * 32 + u * 8 + srow;
        const int ch = sslot ^ ((rl ^ (rl >> 2)) & 7);
        As[u] = A  + (size_t)(m0 + rl) * 1024 + ch * 8;
        Bs[u] = BT + (size_t)(n0 + rl) * 1024 + ch * 8;
        lofs[u] = (unsigned)((w * 32 + u * 8) * 64);
    }

    // prologue: stage k-tile 0 into buffer 0
    #pragma unroll
    for (int u = 0; u < 4; ++u) {
        gload16(As[u], &Ab[0][lofs[u]]);
        gload16(Bs[u], &Bb[0][lofs[u]]);
    }
    __syncthreads();

    // read-side row swizzles
    int rsA[4], rsB[4];
    #pragma unroll
    for (int f = 0; f < 4; ++f) {
        const int ra = wm * 64 + f * 16 + c;
        const int rb = wn * 64 + f * 16 + c;
        rsA[f] = (ra ^ (ra >> 2)) & 7;
        rsB[f] = (rb ^ (rb >> 2)) & 7;
    }

    #pragma unroll 2
    for (int it = 0; it < 16; ++it) {
        const int buf = it & 1;
        // issue next k-tile stage (lands in buf^1; drained by end barrier)
        if (it < 15) {
            #pragma unroll
            for (int u = 0; u < 4; ++u) {
                gload16(As[u] + (it + 1) * 64, &Ab[buf ^ 1][lofs[u]]);
                gload16(Bs[u] + (it + 1) * 64, &Bb[buf ^ 1][lofs[u]]);
            }
        }
        bf16x8 af[4][2], bfr[4][2];
        #pragma unroll
        for (int f = 0; f < 4; ++f)
            #pragma unroll
            for (int kk = 0; kk < 2; ++kk) {
                af[f][kk]  = *(const bf16x8*)&Ab[buf][(wm * 64 + f * 16 + c) * 64 + (((kk * 4 + g) ^ rsA[f]) * 8)];
                bfr[f][kk] = *(const bf16x8*)&Bb[buf][(wn * 64 + f * 16 + c) * 64 + (((kk * 4 + g) ^ rsB[f]) * 8)];
            }
        __builtin_amdgcn_s_setprio(1);
        #pragma unroll
        for (int kk = 0; kk < 2; ++kk)
            #pragma unroll
            for (int mf = 0; mf < 4; ++mf)
                #pragma unroll
                for (int nf = 0; nf < 4; ++nf)
                    acc[mf][nf] = __builtin_amdgcn_mfma_f32_16x16x32_bf16(af[mf][kk], bfr[nf][kk], acc[mf][nf], 0, 0, 0);
        __builtin_amdgcn_s_setprio(0);
        __syncthreads();  // drains vmcnt (next tile) + lgkm, then barrier
    }

    #pragma unroll
    for (int nf = 0; nf < 4; ++nf) {
        const int n = n0 + wn * 64 + nf * 16 + c;
        if (MODE == 0 || (MODE == 3 && n0 < 1024)) {
            const float bv = biasK[n] * bscale;
            const int h = n >> 6, cc = n & 63;
            unsigned short* O = (unsigned short*)OvK;
            #pragma unroll
            for (int mf = 0; mf < 4; ++mf) {
                const int mbase = m0 + wm * 64 + mf * 16 + g * 4;
                const int b = mbase >> 11, t = mbase & 2047;
                #pragma unroll
                for (int r = 0; r < 4; ++r)
                    O[(((size_t)(b * 16 + h)) * 2048 + t + r) * 64 + cc] = f2bf(acc[mf][nf][r] + bv);
            }
        } else if (MODE == 3) {
            const int nn = n - 1024;
            const float bv = biasV[nn];
            const int h = nn >> 6, cc = nn & 63;
            unsigned short* O = (unsigned short*)OvV;
            #pragma unroll
            for (int mf = 0; mf < 4; ++mf) {
                const int mbase = m0 + wm * 64 + mf * 16 + g * 4;
                const int b = mbase >> 11, t = mbase & 2047;
                f32x4 v;
                #pragma unroll
                for (int r = 0; r < 4; ++r) v[r] = acc[mf][nf][r] + bv;
                bf16x4 pv = __builtin_convertvector(v, bf16x4);
                *(bf16x4*)(O + (((size_t)(b * 16 + h)) * 64 + cc) * 2048 + t) = pv;
            }
        } else {
            const float bv = biasK[n] * bscale;
            float* O = (float*)OvK;
            #pragma unroll
            for (int mf = 0; mf < 4; ++mf) {
                const int mbase = m0 + wm * 64 + mf * 16 + g * 4;
                #pragma unroll
                for (int r = 0; r < 4; ++r)
                    O[(size_t)(mbase + r) * 1024 + n] = acc[mf][nf][r] + bv;
            }
        }
    }
}

// ---------------------------------------------------------------------------
// Flash attention, swapped QK^T with PERMUTED K rows (P in registers, K32 PV).
// Each wave handles TWO 16-row t-groups (block = 128 Q rows, grid = 1024 =
// 4 blocks/CU; LDS 4x32KB = 128KB). Shared kf/vf LDS reads feed both groups.
// Flags bitword granularity = one block. setprio around MFMA clusters.
// XCD swizzle: each XCD owns 8 bh x 16 tb (K/V 4MB = L2-resident).
// ---------------------------------------------------------------------------
__global__ __launch_bounds__(256, 4) void attn_kernel(const unsigned short* __restrict__ Qp,
                                                      const unsigned short* __restrict__ Kp,
                                                      const unsigned short* __restrict__ VTp,
                                                      const int* __restrict__ mask,
                                                      const unsigned* __restrict__ flagsW,
                                                      unsigned short* __restrict__ attnb) {
    __shared__ __align__(16) unsigned short Kt[2][64 * 64];  // [s][dk], swizzled chunks
    __shared__ __align__(16) unsigned short Vt[2][64 * 64];  // [v][s],  swizzled chunks

    const int bid = blockIdx.x;
    const int xcd = bid & 7, jj = bid >> 3;       // jj in 0..127
    const int bh = xcd * 8 + (jj >> 4);           // 8 bh per XCD
    const int tb = jj & 15;                       // 16 x 128-row t-tiles
    const int b = bh >> 4, h = bh & 15;
    const int i = threadIdx.x, w = i >> 6, l = i & 63;
    const int c = l & 15, g = l >> 4;

    const unsigned short* Qb  = Qp  + (size_t)bh * 2048 * 64;
    const unsigned short* Kb  = Kp  + (size_t)bh * 2048 * 64;
    const unsigned short* VTb = VTp + (size_t)bh * 64 * 2048;

    const int twave = tb * 128 + w * 32;
    const int tA = twave + c, tB = twave + 16 + c;

    // not-all-true bits for this 128-row region (wave-uniform, to SGPR)
    const unsigned notall = __builtin_amdgcn_readfirstlane(flagsW[b * 16 + tb]);

    // Q as B-operand (K32): lane holds Q[t][dk = kq*32+g*8+j]
    bf16x8 qfA[2], qfB[2];
    #pragma unroll
    for (int kq = 0; kq < 2; ++kq) {
        qfA[kq] = *(const bf16x8*)(Qb + (size_t)tA * 64 + kq * 32 + g * 8);
        qfB[kq] = *(const bf16x8*)(Qb + (size_t)tB * 64 + kq * 32 + g * 8);
    }

    f32x4 oA[4] = {}, oB[4] = {};   // O^T accum: v = vm*16+g*4+r
    f32x4 daccA = {}, daccB = {};   // denominators via ones-MFMA
    const f32x4 zf = {};            // persistent zero C-operand

    bf16x8 ones8;
    #pragma unroll
    for (int j = 0; j < 8; ++j) ones8[j] = (__bf16)1.0f;

    // kf read rows (permuted) + chunk swizzles, per sm
    int rrow[4], rswz[4];
    #pragma unroll
    for (int sm = 0; sm < 4; ++sm) {
        rrow[sm] = (sm >> 1) * 32 + (c >> 2) * 8 + (sm & 1) * 4 + (c & 3);
        rswz[sm] = (rrow[sm] ^ (rrow[sm] >> 2)) & 7;
    }
    int vswz[4];
    #pragma unroll
    for (int vm = 0; vm < 4; ++vm) {
        const int rv = vm * 16 + c;
        vswz[vm] = (rv ^ (rv >> 2)) & 7;
    }

    // staging: lane L -> LDS (row = base + L>>3, slot L&7); source chunk
    // = (L&7) ^ swz(row) so LDS slot s of row r holds global chunk s ^ swz(r).
    const int srow = l >> 3, sslot = l & 7;

    // prologue: stage tile 0 into buffer 0; running stage pointers (tile 1)
    const unsigned short* kstage[2];
    const unsigned short* vstage[2];
    #pragma unroll
    for (int u = 0; u < 2; ++u) {
        const int row = w * 16 + u * 8 + srow;
        const int ch = sslot ^ ((row ^ (row >> 2)) & 7);
        gload16(Kb + (size_t)row * 64 + ch * 8, &Kt[0][(w * 16 + u * 8) * 64]);
        gload16(VTb + (size_t)row * 2048 + ch * 8, &Vt[0][(w * 16 + u * 8) * 64]);
        kstage[u] = Kb + (size_t)(64 + row) * 64 + ch * 8;
        vstage[u] = VTb + (size_t)row * 2048 + 64 + ch * 8;
    }
    __syncthreads();

    #pragma unroll 2
    for (int it = 0; it < 32; ++it) {
        const int buf = it & 1;
        const int s0 = it * 64;

        // issue next-tile stage (lands in buf^1; drained by end-of-iter barrier)
        if (it < 31) {
            #pragma unroll
            for (int u = 0; u < 2; ++u) {
                gload16(kstage[u], &Kt[buf ^ 1][(w * 16 + u * 8) * 64]);
                gload16(vstage[u], &Vt[buf ^ 1][(w * 16 + u * 8) * 64]);
                kstage[u] += 64 * 64;
                vstage[u] += 64;
            }
        }

        // QK^T swapped, permuted rows, both groups sharing kf:
        // scX[sm][r] = S^T at s = s0 + (sm>>1)*32 + g*8 + (sm&1)*4 + r
        f32x4 scA[4], scB[4];
        __builtin_amdgcn_s_setprio(1);
        #pragma unroll
        for (int sm = 0; sm < 4; ++sm) {
            #pragma unroll
            for (int kq = 0; kq < 2; ++kq) {
                const bf16x8 kf = *(const bf16x8*)&Kt[buf][rrow[sm] * 64 + (((kq * 4 + g) ^ rswz[sm]) * 8)];
                if (kq == 0) {
                    scA[sm] = __builtin_amdgcn_mfma_f32_16x16x32_bf16(kf, qfA[0], zf, 0, 0, 0);
                    scB[sm] = __builtin_amdgcn_mfma_f32_16x16x32_bf16(kf, qfB[0], zf, 0, 0, 0);
                } else {
                    scA[sm] = __builtin_amdgcn_mfma_f32_16x16x32_bf16(kf, qfA[1], scA[sm], 0, 0, 0);
                    scB[sm] = __builtin_amdgcn_mfma_f32_16x16x32_bf16(kf, qfB[1], scB[sm], 0, 0, 0);
                }
            }
        }
        __builtin_amdgcn_s_setprio(0);

        // mask fallback (exp2 domain), permuted s indexing (scalar-skipped)
        if (notall & (1u << it)) {
            #pragma unroll
            for (int sm = 0; sm < 4; ++sm)
                #pragma unroll
                for (int r = 0; r < 4; ++r) {
                    const int s = s0 + (sm >> 1) * 32 + g * 8 + (sm & 1) * 4 + r;
                    if (mask[(size_t)(b * 2048 + tA) * 2048 + s] == 0) scA[sm][r] += MASK_ADD;
                    if (mask[(size_t)(b * 2048 + tB) * 2048 + s] == 0) scB[sm][r] += MASK_ADD;
                }
        }

        // p = exp2(sc); pack directly into K32 PV B-fragments
        bf16x8 paA[2], paB[2];
        #pragma unroll
        for (int kv = 0; kv < 2; ++kv) {
            f32x4 a0, a1, b0, b1;
            #pragma unroll
            for (int r = 0; r < 4; ++r) {
                a0[r] = __builtin_amdgcn_exp2f(scA[kv * 2][r]);
                a1[r] = __builtin_amdgcn_exp2f(scA[kv * 2 + 1][r]);
                b0[r] = __builtin_amdgcn_exp2f(scB[kv * 2][r]);
                b1[r] = __builtin_amdgcn_exp2f(scB[kv * 2 + 1][r]);
            }
            union { struct { bf16x4 lo, hi; } hh; bf16x8 v; } ua, ub;
            ua.hh.lo = __builtin_convertvector(a0, bf16x4);
            ua.hh.hi = __builtin_convertvector(a1, bf16x4);
            ub.hh.lo = __builtin_convertvector(b0, bf16x4);
            ub.hh.hi = __builtin_convertvector(b1, bf16x4);
            paA[kv] = ua.v;
            paB[kv] = ub.v;
        }

        // PV (K32) + denominators, shared vf
        __builtin_amdgcn_s_setprio(1);
        #pragma unroll
        for (int kv = 0; kv < 2; ++kv) {
            daccA = __builtin_amdgcn_mfma_f32_16x16x32_bf16(ones8, paA[kv], daccA, 0, 0, 0);
            daccB = __builtin_amdgcn_mfma_f32_16x16x32_bf16(ones8, paB[kv], daccB, 0, 0, 0);
            #pragma unroll
            for (int vm = 0; vm < 4; ++vm) {
                const bf16x8 vf = *(const bf16x8*)&Vt[buf][(vm * 16 + c) * 64 + (((kv * 4 + g) ^ vswz[vm]) * 8)];
                oA[vm] = __builtin_amdgcn_mfma_f32_16x16x32_bf16(vf, paA[kv], oA[vm], 0, 0, 0);
                oB[vm] = __builtin_amdgcn_mfma_f32_16x16x32_bf16(vf, paB[kv], oB[vm], 0, 0, 0);
            }
        }
        __builtin_amdgcn_s_setprio(0);

        __syncthreads();  // drains vmcnt (stage) + lgkm, then barrier
    }

    const float invA = 1.0f / daccA[0];
    const float invB = 1.0f / daccB[0];

    // epilogue: attnb[(b*2048+t)*1024 + h*64 + v] = O^T[v][t] * inv
    #pragma unroll
    for (int vm = 0; vm < 4; ++vm) {
        f32x4 vA, vB;
        #pragma unroll
        for (int r = 0; r < 4; ++r) { vA[r] = oA[vm][r] * invA; vB[r] = oB[vm][r] * invB; }
        bf16x4 pA = __builtin_convertvector(vA, bf16x4);
        bf16x4 pB = __builtin_convertvector(vB, bf16x4);
        *(bf16x4*)(attnb + (size_t)(b * 2048 + tA) * 1024 + h * 64 + vm * 16 + g * 4) = pA;
        *(bf16x4*)(attnb + (size_t)(b * 2048 + tB) * 1024 + h * 64 + vm * 16 + g * 4) = pB;
    }
}

// ---------------------------------------------------------------------------
// Workspace aliasing (peak 73 MB):
//   [0..8)    WqT WkT WvT WoT (2 MB each; WkT||WvT contiguous for merged KV)
//   [8..9)    flagsW
//   [9..25)   VCONV (value bf16)  -> reused as Qp after mm<3>
//   [25..41)  QCONV (query bf16)  -> reused as attnb after mm<0>
//   [41..57)  Kp
//   [57..73)  VTp
// ---------------------------------------------------------------------------
extern "C" void kernel_launch(void* const* d_in, const int* in_sizes, int n_in,
                              void* d_out, int out_size, void* d_ws, size_t ws_size,
                              hipStream_t stream) {
    const float* query = (const float*)d_in[0];
    const float* value = (const float*)d_in[1];
    const int*   mask  = (const int*)d_in[2];
    const float* Wq = (const float*)d_in[3];
    const float* bq = (const float*)d_in[4];
    const float* Wk = (const float*)d_in[5];
    const float* bk = (const float*)d_in[6];
    const float* Wv = (const float*)d_in[7];
    const float* bv = (const float*)d_in[8];
    const float* Wo = (const float*)d_in[9];
    const float* bo = (const float*)d_in[10];

    char* ws = (char*)d_ws;
    unsigned short* WqT   = (unsigned short*)(ws + ((size_t)0  << 20));
    unsigned short* WkT   = (unsigned short*)(ws + ((size_t)2  << 20));
    unsigned short* WvT   = (unsigned short*)(ws + ((size_t)4  << 20));
    unsigned short* WoT   = (unsigned short*)(ws + ((size_t)6  << 20));
    unsigned*       flagsW= (unsigned*)      (ws + ((size_t)8  << 20));
    unsigned short* VCONV = (unsigned short*)(ws + ((size_t)9  << 20));  // -> Qp
    unsigned short* QCONV = (unsigned short*)(ws + ((size_t)25 << 20));  // -> attnb
    unsigned short* Kp    = (unsigned short*)(ws + ((size_t)41 << 20));
    unsigned short* VTp   = (unsigned short*)(ws + ((size_t)57 << 20));
    unsigned short* Qp    = VCONV;   // VCONV dead after mm<3>
    unsigned short* attnb = QCONV;   // QCONV dead after mm<0>

    const int n8 = 8192 * 1024 / 8;

    hipMemsetAsync(flagsW, 0, 64 * sizeof(unsigned), stream);

    // convert value AND query in one launch
    cvt2_kernel<<<2048, 256, 0, stream>>>(value, VCONV, query, QCONV, n8);
    wtrans_kernel<<<dim3(16, 16, 4), 256, 0, stream>>>(Wq, Wk, Wv, Wo, WqT, WkT, WvT, WoT);
    maskflag_kernel<<<2048, 256, 0, stream>>>(mask, flagsW);

    // merged K|V projection (BT = WkT||WvT stacked, N = 2048)
    mm_kernel<3, 16><<<1024, 256, 0, stream>>>(VCONV, WkT, bk, bv, 1.0f, Kp, VTp);
    // Q projection (writes Qp into VCONV's slot - VCONV dead now)
    mm_kernel<0, 8><<<512, 256, 0, stream>>>(QCONV, WqT, bq, bq, C_EXP, Qp, nullptr);

    // attention (writes attnb into QCONV's slot - QCONV dead now)
    attn_kernel<<<1024, 256, 0, stream>>>(Qp, Kp, VTp, mask, flagsW, attnb);

    mm_kernel<2, 8><<<512, 256, 0, stream>>>(attnb, WoT, bo, bo, 1.0f, d_out, nullptr);
}

// Round 15
// 191.997 us; speedup vs baseline: 2.1872x; 1.0533x over previous
//
#include <hip/hip_runtime.h>

typedef __bf16 bf16x8 __attribute__((ext_vector_type(8)));
typedef __bf16 bf16x4 __attribute__((ext_vector_type(4)));
typedef float  f32x4  __attribute__((ext_vector_type(4)));
typedef int    i32x4  __attribute__((ext_vector_type(4)));

typedef __attribute__((address_space(1))) unsigned int as1_u32;
typedef __attribute__((address_space(3))) unsigned int as3_u32;

#define DEVI __device__ __forceinline__

DEVI unsigned short f2bf(float f) {
    union { float f; unsigned u; } v; v.f = f;
    unsigned r = (v.u + 0x7fffu + ((v.u >> 16) & 1u)) >> 16;
    return (unsigned short)r;
}

// direct global->LDS 16B: lane L's 16B lands at ldsbase + L*16
DEVI void gload16(const void* g, void* l) {
    __builtin_amdgcn_global_load_lds((const as1_u32*)g, (as3_u32*)l, 16, 0, 0);
}

// softmax(x/8) = exp2(x * 0.125 * log2(e)); scale folded into Q projection.
#define C_EXP 0.18033688011112042f
// -10000 * log2(e)
#define MASK_ADD (-14426.950408889634f)

// ---------------------------------------------------------------------------
// Fused pre-pass (one launch replaces memset+cvt2+wtrans+maskflag):
//  blocks [0,2048):    f32->bf16 convert of value AND query (grid-stride)
//  blocks [2048,3072): 4x weight transpose W[k][n] -> WT[n][k]*scale
//  blocks [3072,5120): mask not-all-true BYTES (no atomics / no pre-zero):
//                      flagsB[(b*16+tb)*32 + si] = any-zero in 128x64 tile
// ---------------------------------------------------------------------------
__global__ __launch_bounds__(256) void prepass_kernel(const float* __restrict__ value,
                                                      unsigned short* __restrict__ VCONV,
                                                      const float* __restrict__ query,
                                                      unsigned short* __restrict__ QCONV,
                                                      const float* __restrict__ Wq,
                                                      const float* __restrict__ Wk,
                                                      const float* __restrict__ Wv,
                                                      const float* __restrict__ Wo,
                                                      unsigned short* __restrict__ WqT,
                                                      unsigned short* __restrict__ WkT,
                                                      unsigned short* __restrict__ WvT,
                                                      unsigned short* __restrict__ WoT,
                                                      const int* __restrict__ mask,
                                                      unsigned char* __restrict__ flagsB) {
    __shared__ float tile[64][65];
    const int bid = blockIdx.x;
    const int tid = threadIdx.x;

    if (bid < 2048) {
        // --- dual f32 -> bf16 convert ---
        const int n8 = 8192 * 1024 / 8;
        const int total = 2 * n8;
        for (int idx = bid * 256 + tid; idx < total; idx += 2048 * 256) {
            const int sel = idx >= n8;
            const int j = sel ? idx - n8 : idx;
            const float* in = sel ? query : value;
            unsigned short* out = sel ? QCONV : VCONV;
            const f32x4 a = *(const f32x4*)(in + (size_t)j * 8);
            const f32x4 b = *(const f32x4*)(in + (size_t)j * 8 + 4);
            union { bf16x4 v[2]; i32x4 q; } u;
            u.v[0] = __builtin_convertvector(a, bf16x4);
            u.v[1] = __builtin_convertvector(b, bf16x4);
            *(i32x4*)(out + (size_t)j * 8) = u.q;
        }
    } else if (bid < 3072) {
        // --- weight transpose ---
        const int e = bid - 2048;
        const int bx = e & 15, by = (e >> 4) & 15, z = e >> 8;
        const float* W;
        unsigned short* WT;
        float scale = 1.0f;
        switch (z) {
            case 0:  W = Wq; WT = WqT; scale = C_EXP; break;
            case 1:  W = Wk; WT = WkT; break;
            case 2:  W = Wv; WT = WvT; break;
            default: W = Wo; WT = WoT; break;
        }
        const int k0 = bx * 64, n0 = by * 64;
        const int c4 = (tid & 15) * 4, rbase = tid >> 4;
        for (int rr = 0; rr < 4; ++rr) {
            const int kl = rbase + rr * 16;
            const float4 v = *(const float4*)(W + (size_t)(k0 + kl) * 1024 + n0 + c4);
            tile[kl][c4 + 0] = v.x; tile[kl][c4 + 1] = v.y;
            tile[kl][c4 + 2] = v.z; tile[kl][c4 + 3] = v.w;
        }
        __syncthreads();
        for (int rr = 0; rr < 4; ++rr) {
            const int nl = rbase + rr * 16;
            ushort4 o;
            o.x = f2bf(tile[c4 + 0][nl] * scale); o.y = f2bf(tile[c4 + 1][nl] * scale);
            o.z = f2bf(tile[c4 + 2][nl] * scale); o.w = f2bf(tile[c4 + 3][nl] * scale);
            *(ushort4*)(WT + (size_t)(n0 + nl) * 1024 + k0 + c4) = o;
        }
    } else {
        // --- mask flags (bytewise, race-free) ---
        const int e = bid - 3072;
        const int b = e >> 9, rem = e & 511;
        const int tb = rem >> 5, si = rem & 31;
        const int t = tb * 128 + (tid >> 1);
        const int s = si * 64 + (tid & 1) * 32;
        const uint4* p = (const uint4*)(mask + ((size_t)(b * 2048 + t)) * 2048 + s);
        int ok = 1;
        #pragma unroll
        for (int u = 0; u < 8; ++u) {
            const uint4 a = p[u];
            ok &= (a.x != 0) & (a.y != 0) & (a.z != 0) & (a.w != 0);
        }
        int all = __syncthreads_and(ok);
        if (tid == 0) flagsB[(b * 16 + tb) * 32 + si] = (unsigned char)(!all);
    }
}

// ---------------------------------------------------------------------------
// Unified bf16 GEMM (R10 loop, proven): 128x128 tile, BK=64, double-buffered
// global_load_lds staging, XOR chunk-swizzle swz8(r)=(r^(r>>2))&7, XCD grid.
// MODE 0: bf16 Q-scatter [b][h][t][c]   (A = bf16)
// MODE 2: f32 linear [m][n]             (A = bf16)
// MODE 3: merged K|V (N=2048): n<1024 -> K scatter; else V^T scatter.
// MODE 4: merged K|V|Q (N=3072): A = n0<2048 ? A0 : A1; third region Q-scatter.
// ---------------------------------------------------------------------------
template <int MODE, int NB>
__global__ __launch_bounds__(256) void mm_kernel(const unsigned short* __restrict__ A0,
                                                 const unsigned short* __restrict__ A1,
                                                 const unsigned short* __restrict__ BT,
                                                 const float* __restrict__ biasK,
                                                 const float* __restrict__ biasV,
                                                 const float* __restrict__ biasQ,
                                                 float bscale,
                                                 void* __restrict__ OvK,
                                                 void* __restrict__ OvV,
                                                 void* __restrict__ OvQ) {
    __shared__ __align__(16) unsigned short Ab[2][128 * 64];
    __shared__ __align__(16) unsigned short Bb[2][128 * 64];
    const int bid = blockIdx.x;
    const int xcd = bid & 7, jj = bid >> 3;
    const int n0 = (jj % NB) * 128;
    const int m0 = ((jj / NB) * 8 + xcd) * 128;
    const int i = threadIdx.x, w = i >> 6, l = i & 63;
    const int wm = w >> 1, wn = w & 1;
    const int c = l & 15, g = l >> 4;
    const int srow = l >> 3, sslot = l & 7;

    const unsigned short* A = (MODE == 4 && n0 >= 2048) ? A1 : A0;

    f32x4 acc[4][4] = {};

    const unsigned short* As[4];
    const unsigned short* Bs[4];
    unsigned lofs[4];
    #pragma unroll
    for (int u = 0; u < 4; ++u) {
        const int rl = w * 32 + u * 8 + srow;
        const int ch = sslot ^ ((rl ^ (rl >> 2)) & 7);
        As[u] = A  + (size_t)(m0 + rl) * 1024 + ch * 8;
        Bs[u] = BT + (size_t)(n0 + rl) * 1024 + ch * 8;
        lofs[u] = (unsigned)((w * 32 + u * 8) * 64);
    }

    // prologue: stage k-tile 0 into buffer 0
    #pragma unroll
    for (int u = 0; u < 4; ++u) {
        gload16(As[u], &Ab[0][lofs[u]]);
        gload16(Bs[u], &Bb[0][lofs[u]]);
    }
    __syncthreads();

    int rsA[4], rsB[4];
    #pragma unroll
    for (int f = 0; f < 4; ++f) {
        const int ra = wm * 64 + f * 16 + c;
        const int rb = wn * 64 + f * 16 + c;
        rsA[f] = (ra ^ (ra >> 2)) & 7;
        rsB[f] = (rb ^ (rb >> 2)) & 7;
    }

    #pragma unroll 2
    for (int it = 0; it < 16; ++it) {
        const int buf = it & 1;
        if (it < 15) {
            #pragma unroll
            for (int u = 0; u < 4; ++u) {
                gload16(As[u] + (it + 1) * 64, &Ab[buf ^ 1][lofs[u]]);
                gload16(Bs[u] + (it + 1) * 64, &Bb[buf ^ 1][lofs[u]]);
            }
        }
        bf16x8 af[4][2], bfr[4][2];
        #pragma unroll
        for (int f = 0; f < 4; ++f)
            #pragma unroll
            for (int kk = 0; kk < 2; ++kk) {
                af[f][kk]  = *(const bf16x8*)&Ab[buf][(wm * 64 + f * 16 + c) * 64 + (((kk * 4 + g) ^ rsA[f]) * 8)];
                bfr[f][kk] = *(const bf16x8*)&Bb[buf][(wn * 64 + f * 16 + c) * 64 + (((kk * 4 + g) ^ rsB[f]) * 8)];
            }
        __builtin_amdgcn_s_setprio(1);
        #pragma unroll
        for (int kk = 0; kk < 2; ++kk)
            #pragma unroll
            for (int mf = 0; mf < 4; ++mf)
                #pragma unroll
                for (int nf = 0; nf < 4; ++nf)
                    acc[mf][nf] = __builtin_amdgcn_mfma_f32_16x16x32_bf16(af[mf][kk], bfr[nf][kk], acc[mf][nf], 0, 0, 0);
        __builtin_amdgcn_s_setprio(0);
        __syncthreads();
    }

    #pragma unroll
    for (int nf = 0; nf < 4; ++nf) {
        const int n = n0 + wn * 64 + nf * 16 + c;
        const bool isK = (MODE == 0) || ((MODE == 3 || MODE == 4) && n0 < 1024);
        const bool isV = (MODE == 3 || MODE == 4) && n0 >= 1024 && n0 < 2048;
        const bool isQ = (MODE == 4) && n0 >= 2048;
        if (isK) {
            const float bv = biasK[n] * bscale;
            const int h = n >> 6, cc = n & 63;
            unsigned short* O = (unsigned short*)OvK;
            #pragma unroll
            for (int mf = 0; mf < 4; ++mf) {
                const int mbase = m0 + wm * 64 + mf * 16 + g * 4;
                const int b = mbase >> 11, t = mbase & 2047;
                #pragma unroll
                for (int r = 0; r < 4; ++r)
                    O[(((size_t)(b * 16 + h)) * 2048 + t + r) * 64 + cc] = f2bf(acc[mf][nf][r] + bv);
            }
        } else if (isV) {
            const int nn = n - 1024;
            const float bv = biasV[nn];
            const int h = nn >> 6, cc = nn & 63;
            unsigned short* O = (unsigned short*)OvV;
            #pragma unroll
            for (int mf = 0; mf < 4; ++mf) {
                const int mbase = m0 + wm * 64 + mf * 16 + g * 4;
                const int b = mbase >> 11, t = mbase & 2047;
                f32x4 v;
                #pragma unroll
                for (int r = 0; r < 4; ++r) v[r] = acc[mf][nf][r] + bv;
                bf16x4 pv = __builtin_convertvector(v, bf16x4);
                *(bf16x4*)(O + (((size_t)(b * 16 + h)) * 64 + cc) * 2048 + t) = pv;
            }
        } else if (isQ) {
            const int nn = n - 2048;
            const float bv = biasQ[nn] * C_EXP;
            const int h = nn >> 6, cc = nn & 63;
            unsigned short* O = (unsigned short*)OvQ;
            #pragma unroll
            for (int mf = 0; mf < 4; ++mf) {
                const int mbase = m0 + wm * 64 + mf * 16 + g * 4;
                const int b = mbase >> 11, t = mbase & 2047;
                #pragma unroll
                for (int r = 0; r < 4; ++r)
                    O[(((size_t)(b * 16 + h)) * 2048 + t + r) * 64 + cc] = f2bf(acc[mf][nf][r] + bv);
            }
        } else {
            const float bv = biasK[n] * bscale;
            float* O = (float*)OvK;
            #pragma unroll
            for (int mf = 0; mf < 4; ++mf) {
                const int mbase = m0 + wm * 64 + mf * 16 + g * 4;
                #pragma unroll
                for (int r = 0; r < 4; ++r)
                    O[(size_t)(mbase + r) * 1024 + n] = acc[mf][nf][r] + bv;
            }
        }
    }
}

// ---------------------------------------------------------------------------
// Flash attention (unchanged loop): swapped QK^T, permuted K rows, K32 PV,
// two 16-row t-groups per wave, grid 1024 (4 blocks/CU), XOR swizzle, XCD map.
// Flags now BYTES: bitword rebuilt via one byte-load/lane + __ballot.
// ---------------------------------------------------------------------------
__global__ __launch_bounds__(256, 4) void attn_kernel(const unsigned short* __restrict__ Qp,
                                                      const unsigned short* __restrict__ Kp,
                                                      const unsigned short* __restrict__ VTp,
                                                      const int* __restrict__ mask,
                                                      const unsigned char* __restrict__ flagsB,
                                                      unsigned short* __restrict__ attnb) {
    __shared__ __align__(16) unsigned short Kt[2][64 * 64];
    __shared__ __align__(16) unsigned short Vt[2][64 * 64];

    const int bid = blockIdx.x;
    const int xcd = bid & 7, jj = bid >> 3;
    const int bh = xcd * 8 + (jj >> 4);
    const int tb = jj & 15;
    const int b = bh >> 4, h = bh & 15;
    const int i = threadIdx.x, w = i >> 6, l = i & 63;
    const int c = l & 15, g = l >> 4;

    const unsigned short* Qb  = Qp  + (size_t)bh * 2048 * 64;
    const unsigned short* Kb  = Kp  + (size_t)bh * 2048 * 64;
    const unsigned short* VTb = VTp + (size_t)bh * 64 * 2048;

    const int twave = tb * 128 + w * 32;
    const int tA = twave + c, tB = twave + 16 + c;

    // not-all-true bits: lane L loads byte L&31; ballot low word = bitmask
    const unsigned char myb = flagsB[(size_t)(b * 16 + tb) * 32 + (l & 31)];
    const unsigned notall = (unsigned)__ballot(myb != 0);

    bf16x8 qfA[2], qfB[2];
    #pragma unroll
    for (int kq = 0; kq < 2; ++kq) {
        qfA[kq] = *(const bf16x8*)(Qb + (size_t)tA * 64 + kq * 32 + g * 8);
        qfB[kq] = *(const bf16x8*)(Qb + (size_t)tB * 64 + kq * 32 + g * 8);
    }

    f32x4 oA[4] = {}, oB[4] = {};
    f32x4 daccA = {}, daccB = {};
    const f32x4 zf = {};

    bf16x8 ones8;
    #pragma unroll
    for (int j = 0; j < 8; ++j) ones8[j] = (__bf16)1.0f;

    int rrow[4], rswz[4];
    #pragma unroll
    for (int sm = 0; sm < 4; ++sm) {
        rrow[sm] = (sm >> 1) * 32 + (c >> 2) * 8 + (sm & 1) * 4 + (c & 3);
        rswz[sm] = (rrow[sm] ^ (rrow[sm] >> 2)) & 7;
    }
    int vswz[4];
    #pragma unroll
    for (int vm = 0; vm < 4; ++vm) {
        const int rv = vm * 16 + c;
        vswz[vm] = (rv ^ (rv >> 2)) & 7;
    }

    const int srow = l >> 3, sslot = l & 7;

    const unsigned short* kstage[2];
    const unsigned short* vstage[2];
    #pragma unroll
    for (int u = 0; u < 2; ++u) {
        const int row = w * 16 + u * 8 + srow;
        const int ch = sslot ^ ((row ^ (row >> 2)) & 7);
        gload16(Kb + (size_t)row * 64 + ch * 8, &Kt[0][(w * 16 + u * 8) * 64]);
        gload16(VTb + (size_t)row * 2048 + ch * 8, &Vt[0][(w * 16 + u * 8) * 64]);
        kstage[u] = Kb + (size_t)(64 + row) * 64 + ch * 8;
        vstage[u] = VTb + (size_t)row * 2048 + 64 + ch * 8;
    }
    __syncthreads();

    #pragma unroll 2
    for (int it = 0; it < 32; ++it) {
        const int buf = it & 1;
        const int s0 = it * 64;

        if (it < 31) {
            #pragma unroll
            for (int u = 0; u < 2; ++u) {
                gload16(kstage[u], &Kt[buf ^ 1][(w * 16 + u * 8) * 64]);
                gload16(vstage[u], &Vt[buf ^ 1][(w * 16 + u * 8) * 64]);
                kstage[u] += 64 * 64;
                vstage[u] += 64;
            }
        }

        f32x4 scA[4], scB[4];
        __builtin_amdgcn_s_setprio(1);
        #pragma unroll
        for (int sm = 0; sm < 4; ++sm) {
            #pragma unroll
            for (int kq = 0; kq < 2; ++kq) {
                const bf16x8 kf = *(const bf16x8*)&Kt[buf][rrow[sm] * 64 + (((kq * 4 + g) ^ rswz[sm]) * 8)];
                if (kq == 0) {
                    scA[sm] = __builtin_amdgcn_mfma_f32_16x16x32_bf16(kf, qfA[0], zf, 0, 0, 0);
                    scB[sm] = __builtin_amdgcn_mfma_f32_16x16x32_bf16(kf, qfB[0], zf, 0, 0, 0);
                } else {
                    scA[sm] = __builtin_amdgcn_mfma_f32_16x16x32_bf16(kf, qfA[1], scA[sm], 0, 0, 0);
                    scB[sm] = __builtin_amdgcn_mfma_f32_16x16x32_bf16(kf, qfB[1], scB[sm], 0, 0, 0);
                }
            }
        }
        __builtin_amdgcn_s_setprio(0);

        if (notall & (1u << it)) {
            #pragma unroll
            for (int sm = 0; sm < 4; ++sm)
                #pragma unroll
                for (int r = 0; r < 4; ++r) {
                    const int s = s0 + (sm >> 1) * 32 + g * 8 + (sm & 1) * 4 + r;
                    if (mask[(size_t)(b * 2048 + tA) * 2048 + s] == 0) scA[sm][r] += MASK_ADD;
                    if (mask[(size_t)(b * 2048 + tB) * 2048 + s] == 0) scB[sm][r] += MASK_ADD;
                }
        }

        bf16x8 paA[2], paB[2];
        #pragma unroll
        for (int kv = 0; kv < 2; ++kv) {
            f32x4 a0, a1, b0, b1;
            #pragma unroll
            for (int r = 0; r < 4; ++r) {
                a0[r] = __builtin_amdgcn_exp2f(scA[kv * 2][r]);
                a1[r] = __builtin_amdgcn_exp2f(scA[kv * 2 + 1][r]);
                b0[r] = __builtin_amdgcn_exp2f(scB[kv * 2][r]);
                b1[r] = __builtin_amdgcn_exp2f(scB[kv * 2 + 1][r]);
            }
            union { struct { bf16x4 lo, hi; } hh; bf16x8 v; } ua, ub;
            ua.hh.lo = __builtin_convertvector(a0, bf16x4);
            ua.hh.hi = __builtin_convertvector(a1, bf16x4);
            ub.hh.lo = __builtin_convertvector(b0, bf16x4);
            ub.hh.hi = __builtin_convertvector(b1, bf16x4);
            paA[kv] = ua.v;
            paB[kv] = ub.v;
        }

        __builtin_amdgcn_s_setprio(1);
        #pragma unroll
        for (int kv = 0; kv < 2; ++kv) {
            daccA = __builtin_amdgcn_mfma_f32_16x16x32_bf16(ones8, paA[kv], daccA, 0, 0, 0);
            daccB = __builtin_amdgcn_mfma_f32_16x16x32_bf16(ones8, paB[kv], daccB, 0, 0, 0);
            #pragma unroll
            for (int vm = 0; vm < 4; ++vm) {
                const bf16x8 vf = *(const bf16x8*)&Vt[buf][(vm * 16 + c) * 64 + (((kv * 4 + g) ^ vswz[vm]) * 8)];
                oA[vm] = __builtin_amdgcn_mfma_f32_16x16x32_bf16(vf, paA[kv], oA[vm], 0, 0, 0);
                oB[vm] = __builtin_amdgcn_mfma_f32_16x16x32_bf16(vf, paB[kv], oB[vm], 0, 0, 0);
            }
        }
        __builtin_amdgcn_s_setprio(0);

        __syncthreads();
    }

    const float invA = 1.0f / daccA[0];
    const float invB = 1.0f / daccB[0];

    #pragma unroll
    for (int vm = 0; vm < 4; ++vm) {
        f32x4 vA, vB;
        #pragma unroll
        for (int r = 0; r < 4; ++r) { vA[r] = oA[vm][r] * invA; vB[r] = oB[vm][r] * invB; }
        bf16x4 pA = __builtin_convertvector(vA, bf16x4);
        bf16x4 pB = __builtin_convertvector(vB, bf16x4);
        *(bf16x4*)(attnb + (size_t)(b * 2048 + tA) * 1024 + h * 64 + vm * 16 + g * 4) = pA;
        *(bf16x4*)(attnb + (size_t)(b * 2048 + tB) * 1024 + h * 64 + vm * 16 + g * 4) = pB;
    }
}

// ---------------------------------------------------------------------------
// Workspace layout (WkT||WvT||WqT contiguous for merged K|V|Q):
//   [0..2)   WkT   [2..4) WvT   [4..6) WqT   [6..8) WoT   [8..9) flagsB
//   [9..25)  VCONV   [25..41) QCONV (-> attnb)   [41..57) Kp   [57..73) VTp
//   [73..89) Qp (merged path only; fallback aliases Qp = VCONV)
// ---------------------------------------------------------------------------
extern "C" void kernel_launch(void* const* d_in, const int* in_sizes, int n_in,
                              void* d_out, int out_size, void* d_ws, size_t ws_size,
                              hipStream_t stream) {
    const float* query = (const float*)d_in[0];
    const float* value = (const float*)d_in[1];
    const int*   mask  = (const int*)d_in[2];
    const float* Wq = (const float*)d_in[3];
    const float* bq = (const float*)d_in[4];
    const float* Wk = (const float*)d_in[5];
    const float* bk = (const float*)d_in[6];
    const float* Wv = (const float*)d_in[7];
    const float* bv = (const float*)d_in[8];
    const float* Wo = (const float*)d_in[9];
    const float* bo = (const float*)d_in[10];

    char* ws = (char*)d_ws;
    unsigned short* WkT   = (unsigned short*)(ws + ((size_t)0  << 20));
    unsigned short* WvT   = (unsigned short*)(ws + ((size_t)2  << 20));
    unsigned short* WqT   = (unsigned short*)(ws + ((size_t)4  << 20));
    unsigned short* WoT   = (unsigned short*)(ws + ((size_t)6  << 20));
    unsigned char*  flagsB= (unsigned char*) (ws + ((size_t)8  << 20));
    unsigned short* VCONV = (unsigned short*)(ws + ((size_t)9  << 20));
    unsigned short* QCONV = (unsigned short*)(ws + ((size_t)25 << 20));
    unsigned short* Kp    = (unsigned short*)(ws + ((size_t)41 << 20));
    unsigned short* VTp   = (unsigned short*)(ws + ((size_t)57 << 20));

    const bool merged = ws_size >= ((size_t)90 << 20);
    unsigned short* Qp    = merged ? (unsigned short*)(ws + ((size_t)73 << 20)) : VCONV;
    unsigned short* attnb = QCONV;

    // fused pre-pass: cvt(value,query) + 4x wtrans + mask flag bytes
    prepass_kernel<<<5120, 256, 0, stream>>>(value, VCONV, query, QCONV,
                                             Wq, Wk, Wv, Wo, WqT, WkT, WvT, WoT,
                                             mask, flagsB);

    if (merged) {
        // one GEMM for K|V|Q: N = 3072, A per-region (value / query)
        mm_kernel<4, 24><<<1536, 256, 0, stream>>>(VCONV, QCONV, WkT, bk, bv, bq,
                                                   1.0f, Kp, VTp, Qp);
    } else {
        mm_kernel<3, 16><<<1024, 256, 0, stream>>>(VCONV, nullptr, WkT, bk, bv, bq,
                                                   1.0f, Kp, VTp, nullptr);
        mm_kernel<0, 8><<<512, 256, 0, stream>>>(QCONV, nullptr, WqT, bq, bq, bq,
                                                 C_EXP, Qp, nullptr, nullptr);
    }

    attn_kernel<<<1024, 256, 0, stream>>>(Qp, Kp, VTp, mask, flagsB, attnb);

    mm_kernel<2, 8><<<512, 256, 0, stream>>>(attnb, nullptr, WoT, bo, bo, bo,
                                             1.0f, d_out, nullptr, nullptr);
}